// Round 1
// baseline (698.536 us; speedup 1.0000x reference)
//
#include <hip/hip_runtime.h>
#include <math.h>

typedef unsigned short u16;
typedef __bf16 bf16_t;
typedef bf16_t bf16x8 __attribute__((ext_vector_type(8)));
typedef float f32x4 __attribute__((ext_vector_type(4)));

#define DI __device__ __forceinline__

DI u16 f2bf(float f) {
  union { float f; unsigned u; } c; c.f = f;
  unsigned r = c.u + 0x7FFFu + ((c.u >> 16) & 1u);
  return (u16)(r >> 16);
}

typedef __attribute__((address_space(1))) void* gas_ptr;
typedef __attribute__((address_space(3))) void* las_ptr;

DI void gload16(const void* g, void* l) {
  __builtin_amdgcn_global_load_lds((gas_ptr)g, (las_ptr)l, 16, 0, 0);
}

// ---------------- transpose + convert: w [K][N] f32  ->  wt [N][K] bf16 ----------------
__global__ __launch_bounds__(256) void k_transpose(const float* __restrict__ w,
                                                   u16* __restrict__ wt, int K, int N) {
  __shared__ float tile[32][33];
  int n0 = blockIdx.x * 32, k0 = blockIdx.y * 32;
  int tx = threadIdx.x & 31, ty = threadIdx.x >> 5;  // ty 0..7
  for (int r = ty; r < 32; r += 8)
    tile[r][tx] = w[(size_t)(k0 + r) * N + n0 + tx];
  __syncthreads();
  for (int r = ty; r < 32; r += 8)
    wt[(size_t)(n0 + r) * K + k0 + tx] = f2bf(tile[tx][r]);
}

// ---------------- f32 -> bf16 elementwise (vectorized) ----------------
__global__ __launch_bounds__(256) void k_cvt(const float* __restrict__ in, u16* __restrict__ out, int n4) {
  int i = blockIdx.x * 256 + threadIdx.x;
  if (i < n4) {
    float4 v = ((const float4*)in)[i];
    ushort4 o;
    o.x = f2bf(v.x); o.y = f2bf(v.y); o.z = f2bf(v.z); o.w = f2bf(v.w);
    ((ushort4*)out)[i] = o;
  }
}

// ---------------- LayerNorm over C=1024, fp32 in -> bf16 out ----------------
__global__ __launch_bounds__(256) void k_ln(const float* __restrict__ x, const float* __restrict__ g,
                                            const float* __restrict__ b, u16* __restrict__ out) {
  int row = blockIdx.x, t = threadIdx.x;
  const float4 v = ((const float4*)(x + (size_t)row * 1024))[t];
  float s = v.x + v.y + v.z + v.w;
  float ss = v.x * v.x + v.y * v.y + v.z * v.z + v.w * v.w;
  for (int o = 32; o; o >>= 1) { s += __shfl_down(s, o); ss += __shfl_down(ss, o); }
  __shared__ float red[10];
  int w = t >> 6;
  if ((t & 63) == 0) { red[w] = s; red[4 + w] = ss; }
  __syncthreads();
  if (t == 0) {
    float S = red[0] + red[1] + red[2] + red[3];
    float SS = red[4] + red[5] + red[6] + red[7];
    float mean = S * (1.f / 1024.f);
    float var = SS * (1.f / 1024.f) - mean * mean;
    red[8] = mean; red[9] = rsqrtf(var + 1e-6f);
  }
  __syncthreads();
  float mean = red[8], rstd = red[9];
  float4 gg = ((const float4*)g)[t], bb = ((const float4*)b)[t];
  ushort4 o4;
  o4.x = f2bf((v.x - mean) * rstd * gg.x + bb.x);
  o4.y = f2bf((v.y - mean) * rstd * gg.y + bb.y);
  o4.z = f2bf((v.z - mean) * rstd * gg.z + bb.z);
  o4.w = f2bf((v.w - mean) * rstd * gg.w + bb.w);
  ((ushort4*)(out + (size_t)row * 1024))[t] = o4;
}

// ---------------- GEMM: out[M,N] = A[M,K](bf16) @ Bt[N,K](bf16)^T + bias, fused epilogue ----
// MODE 0: bf16 out, *scale after bias (Q/K/V).  MODE 1: f32 out = res + acc + bias.
// MODE 2: bf16 out = gelu(acc + bias).
template <int MODE>
__global__ __launch_bounds__(256) void k_gemm(const u16* __restrict__ A, const u16* __restrict__ Bt,
                                              const float* __restrict__ bias, const float* res,
                                              void* outv, int M, int N, int K, float scale) {
  __shared__ u16 aL[128 * 64];
  __shared__ u16 bL[128 * 64];
  const int lane = threadIdx.x & 63, w = threadIdx.x >> 6;
  const int wm = w >> 1, wn = w & 1;
  const int m0 = blockIdx.y * 128, n0 = blockIdx.x * 128;
  const int lrow = lane >> 3, lc16 = lane & 7;

  f32x4 acc[4][4] = {};
  const int nkt = K >> 6;
  for (int kt = 0; kt < nkt; ++kt) {
    const int k0 = kt << 6;
    // stage A,B tiles: 16 wave-loads each of 1KB; wave w does loads {w,4+w,8+w,12+w}
    for (int i = 0; i < 4; ++i) {
      int r0 = (i * 4 + w) * 8;
      int row = r0 + lrow;
      const char* sa = (const char*)(A + (size_t)(m0 + row) * K + k0) + ((lc16 * 16) ^ ((row & 7) << 4));
      gload16(sa, (char*)aL + r0 * 128);
      const char* sb = (const char*)(Bt + (size_t)(n0 + row) * K + k0) + ((lc16 * 16) ^ ((row & 7) << 4));
      gload16(sb, (char*)bL + r0 * 128);
    }
    __syncthreads();
    for (int kk = 0; kk < 2; ++kk) {
      const int cb = kk * 64 + ((lane >> 4) << 4);
      bf16x8 af[4], bfr[4];
      for (int mi = 0; mi < 4; ++mi) {
        int row = wm * 64 + mi * 16 + (lane & 15);
        af[mi] = *(const bf16x8*)((const char*)aL + row * 128 + (cb ^ ((row & 7) << 4)));
      }
      for (int ni = 0; ni < 4; ++ni) {
        int row = wn * 64 + ni * 16 + (lane & 15);
        bfr[ni] = *(const bf16x8*)((const char*)bL + row * 128 + (cb ^ ((row & 7) << 4)));
      }
      for (int mi = 0; mi < 4; ++mi)
        for (int ni = 0; ni < 4; ++ni)
          acc[mi][ni] = __builtin_amdgcn_mfma_f32_16x16x32_bf16(af[mi], bfr[ni], acc[mi][ni], 0, 0, 0);
    }
    __syncthreads();
  }
  // epilogue: C/D layout col = lane&15, row = (lane>>4)*4 + r
  const int cBase = n0 + wn * 64 + (lane & 15);
  const int rBase = m0 + wm * 64 + ((lane >> 4) << 2);
  for (int ni = 0; ni < 4; ++ni) {
    int col = cBase + ni * 16;
    float bv = bias[col];
    for (int mi = 0; mi < 4; ++mi) {
      int row = rBase + mi * 16;
      f32x4 a = acc[mi][ni];
      for (int r = 0; r < 4; ++r) {
        float v = a[r] + bv;
        size_t idx = (size_t)(row + r) * N + col;
        if (MODE == 0) {
          ((u16*)outv)[idx] = f2bf(v * scale);
        } else if (MODE == 1) {
          ((float*)outv)[idx] = res[idx] + v;
        } else {
          ((u16*)outv)[idx] = f2bf(0.5f * v * (1.f + erff(v * 0.70710678118654752f)));
        }
      }
    }
  }
}

// ---------------- flash attention: Q,K,V bf16 [S][C] (head-strided), O bf16 [S][C] -------
template <bool CAUSAL>
__global__ __launch_bounds__(256) void k_attn(const u16* __restrict__ Q, const u16* __restrict__ K,
                                              const u16* __restrict__ V, u16* __restrict__ O,
                                              int S, int C) {
  __shared__ u16 kL[64 * 64];      // [kv][d]  swizzled
  __shared__ u16 vL[64 * 64];      // [d][kv]  swizzled (transposed at stage)
  __shared__ u16 pL[4][16 * 64];   // per-wave P [q][kv]  swizzled
  const int lane = threadIdx.x & 63, w = threadIdx.x >> 6, t = threadIdx.x;
  const int qt = blockIdx.x, h = blockIdx.y;
  const int hd0 = h * 64;
  const int q0 = qt * 64 + w * 16;

  bf16x8 qf[2];
  for (int kk = 0; kk < 2; ++kk)
    qf[kk] = *(const bf16x8*)(Q + (size_t)(q0 + (lane & 15)) * C + hd0 + kk * 32 + ((lane >> 4) << 3));

  f32x4 o[4] = {};
  float m[4] = {-1e30f, -1e30f, -1e30f, -1e30f};
  float l[4] = {};

  const int nkv = CAUSAL ? (qt + 1) : (S >> 6);
  for (int kt = 0; kt < nkv; ++kt) {
    // stage K (row-major swizzled) and V (transposed swizzled)
    for (int it = 0; it < 2; ++it) {
      int chunk = t + it * 256;
      int r = chunk >> 3, c8 = chunk & 7;
      const u16* ksrc = K + (size_t)(kt * 64 + r) * C + hd0 + c8 * 8;
      *(uint4*)((char*)kL + r * 128 + ((c8 * 16) ^ ((r & 7) << 4))) = *(const uint4*)ksrc;
      union { uint4 q; u16 s[8]; } vu;
      vu.q = *(const uint4*)(V + (size_t)(kt * 64 + r) * C + hd0 + c8 * 8);
      for (int e = 0; e < 8; ++e) {
        int d = c8 * 8 + e;
        *(u16*)((char*)vL + d * 128 + ((r * 2) ^ ((d & 7) << 4))) = vu.s[e];
      }
    }
    __syncthreads();
    // S = Q K^T  (A = Q rows, B = K as [n=kv][k=d] i.e. bt-layout)
    f32x4 s[4];
    for (int n = 0; n < 4; ++n) {
      f32x4 z = {};
      for (int kk = 0; kk < 2; ++kk) {
        int row = n * 16 + (lane & 15);
        int cb = kk * 64 + ((lane >> 4) << 4);
        bf16x8 kf = *(const bf16x8*)((const char*)kL + row * 128 + (cb ^ ((row & 7) << 4)));
        z = __builtin_amdgcn_mfma_f32_16x16x32_bf16(qf[kk], kf, z, 0, 0, 0);
      }
      s[n] = z;
    }
    if (CAUSAL && kt == qt) {
      for (int n = 0; n < 4; ++n)
        for (int r = 0; r < 4; ++r) {
          int qg = q0 + ((lane >> 4) << 2) + r;
          int kg = kt * 64 + n * 16 + (lane & 15);
          if (kg > qg) s[n][r] = -1e30f;
        }
    }
    // online softmax (row lives in 16 lanes: shfl_xor 1,2,4,8)
    float sc[4];
    for (int r = 0; r < 4; ++r) {
      float x = fmaxf(fmaxf(s[0][r], s[1][r]), fmaxf(s[2][r], s[3][r]));
      for (int msk = 1; msk < 16; msk <<= 1) x = fmaxf(x, __shfl_xor(x, msk));
      float mn = fmaxf(m[r], x);
      sc[r] = __expf(m[r] - mn);
      m[r] = mn;
    }
    for (int n = 0; n < 4; ++n)
      for (int r = 0; r < 4; ++r) s[n][r] = __expf(s[n][r] - m[r]);
    for (int r = 0; r < 4; ++r) {
      float x = s[0][r] + s[1][r] + s[2][r] + s[3][r];
      for (int msk = 1; msk < 16; msk <<= 1) x += __shfl_xor(x, msk);
      l[r] = l[r] * sc[r] + x;
    }
    for (int n = 0; n < 4; ++n) {
      o[n][0] *= sc[0]; o[n][1] *= sc[1]; o[n][2] *= sc[2]; o[n][3] *= sc[3];
    }
    // P -> per-wave LDS (bf16, swizzled), then PV
    for (int n = 0; n < 4; ++n)
      for (int r = 0; r < 4; ++r) {
        int prow = ((lane >> 4) << 2) + r;
        int cbyte = (n * 16 + (lane & 15)) * 2;
        *(u16*)((char*)pL[w] + prow * 128 + (cbyte ^ ((prow & 7) << 4))) = f2bf(s[n][r]);
      }
    for (int kk = 0; kk < 2; ++kk) {
      int arow = lane & 15;
      int acb = kk * 64 + ((lane >> 4) << 4);
      bf16x8 pf = *(const bf16x8*)((const char*)pL[w] + arow * 128 + (acb ^ ((arow & 7) << 4)));
      for (int n = 0; n < 4; ++n) {
        int vrow = n * 16 + (lane & 15);
        bf16x8 vf = *(const bf16x8*)((const char*)vL + vrow * 128 + (acb ^ ((vrow & 7) << 4)));
        o[n] = __builtin_amdgcn_mfma_f32_16x16x32_bf16(pf, vf, o[n], 0, 0, 0);
      }
    }
    __syncthreads();
  }
  for (int n = 0; n < 4; ++n)
    for (int r = 0; r < 4; ++r) {
      int qg = q0 + ((lane >> 4) << 2) + r;
      int dg = hd0 + n * 16 + (lane & 15);
      O[(size_t)qg * C + dg] = f2bf(o[n][r] / l[r]);
    }
}

// ==========================================================================================
extern "C" void kernel_launch(void* const* d_in, const int* in_sizes, int n_in,
                              void* d_out, int out_size, void* d_ws, size_t ws_size,
                              hipStream_t stream) {
  const float* features = (const float*)d_in[0];
  const float* enc      = (const float*)d_in[1];
  const float* g1a = (const float*)d_in[2];  const float* b1a = (const float*)d_in[3];
  const float* g1b = (const float*)d_in[4];  const float* b1b = (const float*)d_in[5];
  const float* g2a = (const float*)d_in[6];  const float* b2a = (const float*)d_in[7];
  const float* g2b = (const float*)d_in[8];  const float* b2b = (const float*)d_in[9];
  const float* sa_qw = (const float*)d_in[10]; const float* sa_qb = (const float*)d_in[11];
  const float* sa_kw = (const float*)d_in[12]; const float* sa_kb = (const float*)d_in[13];
  const float* sa_vw = (const float*)d_in[14]; const float* sa_vb = (const float*)d_in[15];
  const float* sa_pw = (const float*)d_in[16]; const float* sa_pb = (const float*)d_in[17];
  const float* ca_qw = (const float*)d_in[18]; const float* ca_qb = (const float*)d_in[19];
  const float* ca_kw = (const float*)d_in[20]; const float* ca_kb = (const float*)d_in[21];
  const float* ca_vw = (const float*)d_in[22]; const float* ca_vb = (const float*)d_in[23];
  const float* ca_pw = (const float*)d_in[24]; const float* ca_pb = (const float*)d_in[25];
  const float* m1_w1 = (const float*)d_in[26]; const float* m1_b1 = (const float*)d_in[27];
  const float* m1_w2 = (const float*)d_in[28]; const float* m1_b2 = (const float*)d_in[29];
  const float* m2_w1 = (const float*)d_in[30]; const float* m2_b1 = (const float*)d_in[31];
  const float* m2_w2 = (const float*)d_in[32]; const float* m2_b2 = (const float*)d_in[33];

  const int S = 2048, C = 1024, Mh = 4096;
  float* xout = (float*)d_out;

  char* p = (char*)d_ws;
  auto take = [&](size_t bytes) { char* q = p; p += (bytes + 255) & ~(size_t)255; return q; };
  u16* wt_saq = (u16*)take((size_t)C * C * 2);
  u16* wt_sak = (u16*)take((size_t)C * C * 2);
  u16* wt_sav = (u16*)take((size_t)C * C * 2);
  u16* wt_sap = (u16*)take((size_t)C * C * 2);
  u16* wt_caq = (u16*)take((size_t)C * C * 2);
  u16* wt_cak = (u16*)take((size_t)C * C * 2);
  u16* wt_cav = (u16*)take((size_t)C * C * 2);
  u16* wt_cap = (u16*)take((size_t)C * C * 2);
  u16* wt_m1w1 = (u16*)take((size_t)C * Mh * 2);
  u16* wt_m1w2 = (u16*)take((size_t)C * Mh * 2);
  u16* wt_m2w1 = (u16*)take((size_t)C * Mh * 2);
  u16* wt_m2w2 = (u16*)take((size_t)C * Mh * 2);
  u16* xn   = (u16*)take((size_t)S * C * 2);
  u16* qbuf = (u16*)take((size_t)S * C * 2);
  u16* kbuf = (u16*)take((size_t)S * C * 2);
  u16* vbuf = (u16*)take((size_t)S * C * 2);
  u16* hbuf = (u16*)take((size_t)S * Mh * 2);  // attn-out (4MB) / MLP hidden (16MB)
  u16* encb = (u16*)take((size_t)S * C * 2);

  dim3 blk(256);
  // --- weights -> bf16 transposed [N][K]
  k_transpose<<<dim3(C / 32, C / 32), blk, 0, stream>>>(sa_qw, wt_saq, C, C);
  k_transpose<<<dim3(C / 32, C / 32), blk, 0, stream>>>(sa_kw, wt_sak, C, C);
  k_transpose<<<dim3(C / 32, C / 32), blk, 0, stream>>>(sa_vw, wt_sav, C, C);
  k_transpose<<<dim3(C / 32, C / 32), blk, 0, stream>>>(sa_pw, wt_sap, C, C);
  k_transpose<<<dim3(C / 32, C / 32), blk, 0, stream>>>(ca_qw, wt_caq, C, C);
  k_transpose<<<dim3(C / 32, C / 32), blk, 0, stream>>>(ca_kw, wt_cak, C, C);
  k_transpose<<<dim3(C / 32, C / 32), blk, 0, stream>>>(ca_vw, wt_cav, C, C);
  k_transpose<<<dim3(C / 32, C / 32), blk, 0, stream>>>(ca_pw, wt_cap, C, C);
  k_transpose<<<dim3(Mh / 32, C / 32), blk, 0, stream>>>(m1_w1, wt_m1w1, C, Mh);
  k_transpose<<<dim3(C / 32, Mh / 32), blk, 0, stream>>>(m1_w2, wt_m1w2, Mh, C);
  k_transpose<<<dim3(Mh / 32, C / 32), blk, 0, stream>>>(m2_w1, wt_m2w1, C, Mh);
  k_transpose<<<dim3(C / 32, Mh / 32), blk, 0, stream>>>(m2_w2, wt_m2w2, Mh, C);
  k_cvt<<<dim3(S * C / 1024), blk, 0, stream>>>(enc, encb, S * C / 4);

  const float qs = 0.125f;  // hd^-0.5, hd=64

  // --- block 1: self-attention (causal)
  k_ln<<<S, blk, 0, stream>>>(features, g1a, b1a, xn);
  k_gemm<0><<<dim3(C / 128, S / 128), blk, 0, stream>>>(xn, wt_saq, sa_qb, nullptr, qbuf, S, C, C, qs);
  k_gemm<0><<<dim3(C / 128, S / 128), blk, 0, stream>>>(xn, wt_sak, sa_kb, nullptr, kbuf, S, C, C, 1.f);
  k_gemm<0><<<dim3(C / 128, S / 128), blk, 0, stream>>>(xn, wt_sav, sa_vb, nullptr, vbuf, S, C, C, 1.f);
  k_attn<true><<<dim3(S / 64, 16), blk, 0, stream>>>(qbuf, kbuf, vbuf, hbuf, S, C);
  k_gemm<1><<<dim3(C / 128, S / 128), blk, 0, stream>>>(hbuf, wt_sap, sa_pb, features, xout, S, C, C, 1.f);
  // --- MLP 1
  k_ln<<<S, blk, 0, stream>>>(xout, g1b, b1b, xn);
  k_gemm<2><<<dim3(Mh / 128, S / 128), blk, 0, stream>>>(xn, wt_m1w1, m1_b1, nullptr, hbuf, S, Mh, C, 1.f);
  k_gemm<1><<<dim3(C / 128, S / 128), blk, 0, stream>>>(hbuf, wt_m1w2, m1_b2, xout, xout, S, C, Mh, 1.f);
  // --- block 2: cross-attention (k,v from encoder)
  k_ln<<<S, blk, 0, stream>>>(xout, g2a, b2a, xn);
  k_gemm<0><<<dim3(C / 128, S / 128), blk, 0, stream>>>(xn, wt_caq, ca_qb, nullptr, qbuf, S, C, C, qs);
  k_gemm<0><<<dim3(C / 128, S / 128), blk, 0, stream>>>(encb, wt_cak, ca_kb, nullptr, kbuf, S, C, C, 1.f);
  k_gemm<0><<<dim3(C / 128, S / 128), blk, 0, stream>>>(encb, wt_cav, ca_vb, nullptr, vbuf, S, C, C, 1.f);
  k_attn<false><<<dim3(S / 64, 16), blk, 0, stream>>>(qbuf, kbuf, vbuf, hbuf, S, C);
  k_gemm<1><<<dim3(C / 128, S / 128), blk, 0, stream>>>(hbuf, wt_cap, ca_pb, xout, xout, S, C, C, 1.f);
  // --- MLP 2
  k_ln<<<S, blk, 0, stream>>>(xout, g2b, b2b, xn);
  k_gemm<2><<<dim3(Mh / 128, S / 128), blk, 0, stream>>>(xn, wt_m2w1, m2_b1, nullptr, hbuf, S, Mh, C, 1.f);
  k_gemm<1><<<dim3(C / 128, S / 128), blk, 0, stream>>>(hbuf, wt_m2w2, m2_b2, xout, xout, S, C, Mh, 1.f);
}

// Round 4
// 500.490 us; speedup vs baseline: 1.3957x; 1.3957x over previous
//
#include <hip/hip_runtime.h>
#include <math.h>

typedef unsigned short u16;
typedef __bf16 bf16_t;
typedef bf16_t bf16x8 __attribute__((ext_vector_type(8)));
typedef float f32x4 __attribute__((ext_vector_type(4)));
typedef float f32x16 __attribute__((ext_vector_type(16)));

#define DI __device__ __forceinline__

DI u16 f2bf(float f) {
  union { float f; unsigned u; } c; c.f = f;
  unsigned r = c.u + 0x7FFFu + ((c.u >> 16) & 1u);
  return (u16)(r >> 16);
}

DI unsigned pack2(float lo, float hi_) {
  return (unsigned)f2bf(lo) | ((unsigned)f2bf(hi_) << 16);
}

typedef __attribute__((address_space(1))) void* gas_ptr;
typedef __attribute__((address_space(3))) void* las_ptr;

DI void gload16(const void* g, void* l) {
  __builtin_amdgcn_global_load_lds((gas_ptr)g, (las_ptr)l, 16, 0, 0);
}

// ---------------- transpose + convert: w [K][N] f32  ->  wt [N][K] bf16 ----------------
__global__ __launch_bounds__(256) void k_transpose(const float* __restrict__ w,
                                                   u16* __restrict__ wt, int K, int N) {
  __shared__ float tile[32][33];
  int n0 = blockIdx.x * 32, k0 = blockIdx.y * 32;
  int tx = threadIdx.x & 31, ty = threadIdx.x >> 5;
  for (int r = ty; r < 32; r += 8)
    tile[r][tx] = w[(size_t)(k0 + r) * N + n0 + tx];
  __syncthreads();
  for (int r = ty; r < 32; r += 8)
    wt[(size_t)(n0 + r) * K + k0 + tx] = f2bf(tile[tx][r]);
}

// ---------------- f32 -> bf16 elementwise ----------------
__global__ __launch_bounds__(256) void k_cvt(const float* __restrict__ in, u16* __restrict__ out, int n4) {
  int i = blockIdx.x * 256 + threadIdx.x;
  if (i < n4) {
    float4 v = ((const float4*)in)[i];
    ushort4 o;
    o.x = f2bf(v.x); o.y = f2bf(v.y); o.z = f2bf(v.z); o.w = f2bf(v.w);
    ((ushort4*)out)[i] = o;
  }
}

// ---------------- f32 copy (bias packing) ----------------
__global__ __launch_bounds__(256) void k_copyf(float* __restrict__ dst, const float* __restrict__ src, int n) {
  int i = blockIdx.x * 256 + threadIdx.x;
  if (i < n) dst[i] = src[i];
}

// ---------------- LayerNorm over C=1024, fp32 in -> bf16 out ----------------
__global__ __launch_bounds__(256) void k_ln(const float* __restrict__ x, const float* __restrict__ g,
                                            const float* __restrict__ b, u16* __restrict__ out) {
  int row = blockIdx.x, t = threadIdx.x;
  const float4 v = ((const float4*)(x + (size_t)row * 1024))[t];
  float s = v.x + v.y + v.z + v.w;
  float ss = v.x * v.x + v.y * v.y + v.z * v.z + v.w * v.w;
  for (int o = 32; o; o >>= 1) { s += __shfl_down(s, o); ss += __shfl_down(ss, o); }
  __shared__ float red[10];
  int w = t >> 6;
  if ((t & 63) == 0) { red[w] = s; red[4 + w] = ss; }
  __syncthreads();
  if (t == 0) {
    float S = red[0] + red[1] + red[2] + red[3];
    float SS = red[4] + red[5] + red[6] + red[7];
    float mean = S * (1.f / 1024.f);
    float var = SS * (1.f / 1024.f) - mean * mean;
    red[8] = mean; red[9] = rsqrtf(var + 1e-6f);
  }
  __syncthreads();
  float mean = red[8], rstd = red[9];
  float4 gg = ((const float4*)g)[t], bb = ((const float4*)b)[t];
  ushort4 o4;
  o4.x = f2bf((v.x - mean) * rstd * gg.x + bb.x);
  o4.y = f2bf((v.y - mean) * rstd * gg.y + bb.y);
  o4.z = f2bf((v.z - mean) * rstd * gg.z + bb.z);
  o4.w = f2bf((v.w - mean) * rstd * gg.w + bb.w);
  ((ushort4*)(out + (size_t)row * 1024))[t] = o4;
}

// ---------------- GEMM: out[M,N] = A[M,K](bf16) @ Bt[N,K]^T + bias ----------------
// MODE 0: bf16 out (scale cols < scale_end); cols >= vcol0 written TRANSPOSED to vtout.
// MODE 1: f32 out = res + acc + bias.   MODE 2: bf16 out = gelu(acc + bias).
template <int MODE, int BM>
__global__ __launch_bounds__(256) void k_gemm(const u16* __restrict__ A, const u16* __restrict__ Bt,
                                              const float* __restrict__ bias, const float* res,
                                              void* outv, u16* vtout, int M, int N, int K,
                                              int ostride, float scale, int scale_end, int vcol0) {
  constexpr int NT = (BM == 128) ? 4 : 2;
  __shared__ u16 aL[BM * 64];
  __shared__ u16 bL[128 * 64];
  const int lane = threadIdx.x & 63, w = threadIdx.x >> 6, t = threadIdx.x;
  const int wm = (BM == 128) ? (w >> 1) : 0;
  const int wn = (BM == 128) ? (w & 1) : w;
  const int m0 = blockIdx.y * BM, n0 = blockIdx.x * 128;

  f32x4 acc[4][NT];
#pragma unroll
  for (int i = 0; i < 4; ++i)
#pragma unroll
    for (int j = 0; j < NT; ++j) acc[i][j] = (f32x4){0.f, 0.f, 0.f, 0.f};

  const int nkt = K >> 6;
  for (int kt = 0; kt < nkt; ++kt) {
    const int k0 = kt << 6;
#pragma unroll
    for (int c = t; c < BM * 8; c += 256) {
      int row = c >> 3, c16 = c & 7;
      int sw = (c16 * 16) ^ ((row & 7) << 4);
      gload16((const char*)(A + (size_t)(m0 + row) * K + k0) + sw, (char*)aL + c * 16);
    }
#pragma unroll
    for (int c = t; c < 1024; c += 256) {
      int row = c >> 3, c16 = c & 7;
      int sw = (c16 * 16) ^ ((row & 7) << 4);
      gload16((const char*)(Bt + (size_t)(n0 + row) * K + k0) + sw, (char*)bL + c * 16);
    }
    __syncthreads();
#pragma unroll
    for (int kk = 0; kk < 2; ++kk) {
      const int cb = kk * 64 + ((lane >> 4) << 4);
      bf16x8 af[4], bfr[NT];
#pragma unroll
      for (int mi = 0; mi < 4; ++mi) {
        int row = wm * 64 + mi * 16 + (lane & 15);
        af[mi] = *(const bf16x8*)((const char*)aL + row * 128 + (cb ^ ((row & 7) << 4)));
      }
#pragma unroll
      for (int ni = 0; ni < NT; ++ni) {
        int row = wn * (NT * 16) + ni * 16 + (lane & 15);
        bfr[ni] = *(const bf16x8*)((const char*)bL + row * 128 + (cb ^ ((row & 7) << 4)));
      }
#pragma unroll
      for (int mi = 0; mi < 4; ++mi)
#pragma unroll
        for (int ni = 0; ni < NT; ++ni)
          acc[mi][ni] = __builtin_amdgcn_mfma_f32_16x16x32_bf16(af[mi], bfr[ni], acc[mi][ni], 0, 0, 0);
    }
    __syncthreads();
  }

  const int cBase = n0 + wn * (NT * 16) + (lane & 15);
  const int rBase = m0 + wm * 64 + ((lane >> 4) << 2);
#pragma unroll
  for (int ni = 0; ni < NT; ++ni) {
    int col = cBase + ni * 16;
    float bv = bias[col];
#pragma unroll
    for (int mi = 0; mi < 4; ++mi) {
      int row = rBase + mi * 16;
      f32x4 a = acc[mi][ni];
      if (MODE == 0) {
        float sc = (col < scale_end) ? scale : 1.f;
        if (col >= vcol0) {
          ushort4 o4;
          o4.x = f2bf((a[0] + bv) * sc); o4.y = f2bf((a[1] + bv) * sc);
          o4.z = f2bf((a[2] + bv) * sc); o4.w = f2bf((a[3] + bv) * sc);
          *(ushort4*)(vtout + (size_t)(col - vcol0) * M + row) = o4;
        } else {
#pragma unroll
          for (int r = 0; r < 4; ++r)
            ((u16*)outv)[(size_t)(row + r) * ostride + col] = f2bf((a[r] + bv) * sc);
        }
      } else if (MODE == 1) {
#pragma unroll
        for (int r = 0; r < 4; ++r) {
          size_t idx = (size_t)(row + r) * ostride + col;
          ((float*)outv)[idx] = res[idx] + a[r] + bv;
        }
      } else {
#pragma unroll
        for (int r = 0; r < 4; ++r) {
          float v = a[r] + bv;
          ((u16*)outv)[(size_t)(row + r) * ostride + col] =
              f2bf(0.5f * v * (1.f + erff(v * 0.70710678118654752f)));
        }
      }
    }
  }
}

// ---------------- flash attention, swapped 32x32 structure (direction-safe) --------------
// Q [S][qstride] (pre-scaled by hd^-0.5*log2e), K [S][kstride], VT [1024][S], O [S][1024].
// Block: 256 threads = 4 waves, each wave owns 32 q-rows (QBLK=128); KV tile 64.
template <bool CAUSAL>
__global__ __launch_bounds__(256) void k_attn2(const u16* __restrict__ Q, const u16* __restrict__ K,
                                               const u16* __restrict__ VT, u16* __restrict__ O,
                                               int S, int qstride, int kstride) {
  __shared__ u16 smem[2][64 * 64];  // [0]=K [kv][d] swz, [1]=V^T [d][kv] swz; epilogue: O tile
  u16* kL = smem[0];
  u16* vL = smem[1];
  const int t = threadIdx.x, lane = t & 63, w = t >> 6;
  const int lo5 = lane & 31, hi = lane >> 5;
  const int qt = blockIdx.x, h = blockIdx.y, hd0 = h * 64;
  const int q0 = qt * 128 + w * 32;

  // Q fragments (B-operand): col=q=lane&31, k(d-local) = sl*16 + hi*8 + e
  bf16x8 qf[4];
#pragma unroll
  for (int sl = 0; sl < 4; ++sl)
    qf[sl] = *(const bf16x8*)(Q + (size_t)(q0 + lo5) * qstride + hd0 + sl * 16 + hi * 8);

  f32x16 oa0 = {}, oa1 = {};  // O^T: d rows [0..31],[32..63], col q = lane&31
  float mrun = -1e30f, lsum = 0.f;

  const int nkt = CAUSAL ? (2 * qt + 2) : (S >> 6);
  for (int kt = 0; kt < nkt; ++kt) {
    // stage K [64 kv][64 d] and V^T [64 d][64 kv], pre-swizzled source -> linear LDS
#pragma unroll
    for (int i = 0; i < 2; ++i) {
      int c = i * 256 + t, row = c >> 3, c16 = c & 7;
      int sw = (c16 * 16) ^ ((row & 7) << 4);
      gload16((const char*)(K + (size_t)(kt * 64 + row) * kstride + hd0) + sw, (char*)kL + c * 16);
    }
#pragma unroll
    for (int i = 0; i < 2; ++i) {
      int c = i * 256 + t, row = c >> 3, c16 = c & 7;
      int sw = (c16 * 16) ^ ((row & 7) << 4);
      gload16((const char*)(VT + (size_t)(hd0 + row) * S + kt * 64) + sw, (char*)vL + c * 16);
    }
    __syncthreads();

    // S^T[kv][q] = K · Q^T : col=q=lane&31, row=kv=(r&3)+8*(r>>2)+4*hi (+32 for s1)
    f32x16 s0 = {}, s1 = {};
#pragma unroll
    for (int sl = 0; sl < 4; ++sl) {
      int cb = sl * 32 + hi * 16;
      int r0 = lo5, r1 = 32 + lo5;
      bf16x8 kf0 = *(const bf16x8*)((const char*)kL + r0 * 128 + (cb ^ ((r0 & 7) << 4)));
      bf16x8 kf1 = *(const bf16x8*)((const char*)kL + r1 * 128 + (cb ^ ((r1 & 7) << 4)));
      s0 = __builtin_amdgcn_mfma_f32_32x32x16_bf16(kf0, qf[sl], s0, 0, 0, 0);
      s1 = __builtin_amdgcn_mfma_f32_32x32x16_bf16(kf1, qf[sl], s1, 0, 0, 0);
    }

    if (CAUSAL && kt >= 2 * qt) {
      int qg = q0 + lo5;
#pragma unroll
      for (int r = 0; r < 16; ++r) {
        int kg = kt * 64 + (r & 3) + 8 * (r >> 2) + 4 * hi;
        if (kg > qg) s0[r] = -1e30f;
        if (kg + 32 > qg) s1[r] = -1e30f;
      }
    }

    // row max over 64 kv: 31 in-lane + cross-half shfl_xor(32)
    float pm = s0[0];
#pragma unroll
    for (int r = 1; r < 16; ++r) pm = fmaxf(pm, s0[r]);
#pragma unroll
    for (int r = 0; r < 16; ++r) pm = fmaxf(pm, s1[r]);
    pm = fmaxf(pm, __shfl_xor(pm, 32));

    float mnew = fmaxf(mrun, pm);
    float sc = exp2f(mrun - mnew);
    lsum *= sc;
#pragma unroll
    for (int r = 0; r < 16; ++r) { oa0[r] *= sc; oa1[r] *= sc; }
    mrun = mnew;

    float ps = 0.f;
#pragma unroll
    for (int r = 0; r < 16; ++r) { s0[r] = exp2f(s0[r] - mrun); ps += s0[r]; }
#pragma unroll
    for (int r = 0; r < 16; ++r) { s1[r] = exp2f(s1[r] - mrun); ps += s1[r]; }
    ps += __shfl_xor(ps, 32);
    lsum += ps;

    // P fragments (B-operand: element e at lane(q,hi) = P[q][kv=ks*16+hi*8+e]);
    // PV: O^T += V^T · P^T
#pragma unroll
    for (int ks = 0; ks < 4; ++ks) {
      const int base = 8 * (ks & 1);
      float pA0, pA1, pA2, pA3, pB0, pB1, pB2, pB3;
      if (ks < 2) {
        pA0 = s0[base + 0]; pA1 = s0[base + 1]; pA2 = s0[base + 2]; pA3 = s0[base + 3];
        pB0 = s0[base + 4]; pB1 = s0[base + 5]; pB2 = s0[base + 6]; pB3 = s0[base + 7];
      } else {
        pA0 = s1[base + 0]; pA1 = s1[base + 1]; pA2 = s1[base + 2]; pA3 = s1[base + 3];
        pB0 = s1[base + 4]; pB1 = s1[base + 5]; pB2 = s1[base + 6]; pB3 = s1[base + 7];
      }
      // self pA[j] = kv ks*16 + j + 4hi ; self pB[j] = kv ks*16 + 8 + j + 4hi
      unsigned a01 = pack2(pA0, pA1), a23 = pack2(pA2, pA3);
      unsigned b01 = pack2(pB0, pB1), b23 = pack2(pB2, pB3);
      unsigned xa01 = __shfl_xor(a01, 32), xa23 = __shfl_xor(a23, 32);
      unsigned xb01 = __shfl_xor(b01, 32), xb23 = __shfl_xor(b23, 32);
      union { unsigned u[4]; bf16x8 v; } pf;
      pf.u[0] = hi ? xb01 : a01;   // e0,e1: kv ks*16 + hi*8 + {0,1}
      pf.u[1] = hi ? xb23 : a23;   // e2,e3
      pf.u[2] = hi ? b01 : xa01;   // e4,e5
      pf.u[3] = hi ? b23 : xa23;   // e6,e7
      int cb = ks * 32 + hi * 16;
      int r0 = lo5, r1 = 32 + lo5;
      bf16x8 vf0 = *(const bf16x8*)((const char*)vL + r0 * 128 + (cb ^ ((r0 & 7) << 4)));
      bf16x8 vf1 = *(const bf16x8*)((const char*)vL + r1 * 128 + (cb ^ ((r1 & 7) << 4)));
      oa0 = __builtin_amdgcn_mfma_f32_32x32x16_bf16(vf0, pf.v, oa0, 0, 0, 0);
      oa1 = __builtin_amdgcn_mfma_f32_32x32x16_bf16(vf1, pf.v, oa1, 0, 0, 0);
    }
    __syncthreads();
  }

  // epilogue: O^T regs -> ldsO[q][d] (swizzled, 64 d = 128B per row) -> coalesced global
  float inv = 1.f / lsum;
  u16* ldsO = smem[0];  // 128 rows x 128B = 16KB (spans both buffers)
  int qrow = w * 32 + lo5;
#pragma unroll
  for (int g = 0; g < 4; ++g) {
    // oa0[4g+j] = d(8g+4hi+j), oa1[4g+j] = d(32+8g+4hi+j)
    unsigned w0 = pack2(oa0[4 * g + 0] * inv, oa0[4 * g + 1] * inv);
    unsigned w1 = pack2(oa0[4 * g + 2] * inv, oa0[4 * g + 3] * inv);
    int dby = (8 * g + 4 * hi) * 2;
    *(uint2*)((char*)ldsO + qrow * 128 + (dby ^ ((qrow & 7) << 4))) = make_uint2(w0, w1);
    unsigned w2 = pack2(oa1[4 * g + 0] * inv, oa1[4 * g + 1] * inv);
    unsigned w3 = pack2(oa1[4 * g + 2] * inv, oa1[4 * g + 3] * inv);
    int dby2 = (32 + 8 * g + 4 * hi) * 2;  // FIX: d=32+8g+4hi -> byte offset (d)*2 (was 128+)
    *(uint2*)((char*)ldsO + qrow * 128 + (dby2 ^ ((qrow & 7) << 4))) = make_uint2(w2, w3);
  }
  __syncthreads();
#pragma unroll
  for (int i = 0; i < 4; ++i) {
    int c = i * 256 + t, row = c >> 3, c16 = c & 7;
    uint4 val = *(const uint4*)((const char*)ldsO + row * 128 + ((c16 * 16) ^ ((row & 7) << 4)));
    *(uint4*)(O + (size_t)(qt * 128 + row) * 1024 + hd0 + c16 * 8) = val;
  }
}

// ==========================================================================================
extern "C" void kernel_launch(void* const* d_in, const int* in_sizes, int n_in,
                              void* d_out, int out_size, void* d_ws, size_t ws_size,
                              hipStream_t stream) {
  const float* features = (const float*)d_in[0];
  const float* enc      = (const float*)d_in[1];
  const float* g1a = (const float*)d_in[2];  const float* b1a = (const float*)d_in[3];
  const float* g1b = (const float*)d_in[4];  const float* b1b = (const float*)d_in[5];
  const float* g2a = (const float*)d_in[6];  const float* b2a = (const float*)d_in[7];
  const float* g2b = (const float*)d_in[8];  const float* b2b = (const float*)d_in[9];
  const float* sa_qw = (const float*)d_in[10]; const float* sa_qb = (const float*)d_in[11];
  const float* sa_kw = (const float*)d_in[12]; const float* sa_kb = (const float*)d_in[13];
  const float* sa_vw = (const float*)d_in[14]; const float* sa_vb = (const float*)d_in[15];
  const float* sa_pw = (const float*)d_in[16]; const float* sa_pb = (const float*)d_in[17];
  const float* ca_qw = (const float*)d_in[18]; const float* ca_qb = (const float*)d_in[19];
  const float* ca_kw = (const float*)d_in[20]; const float* ca_kb = (const float*)d_in[21];
  const float* ca_vw = (const float*)d_in[22]; const float* ca_vb = (const float*)d_in[23];
  const float* ca_pw = (const float*)d_in[24]; const float* ca_pb = (const float*)d_in[25];
  const float* m1_w1 = (const float*)d_in[26]; const float* m1_b1 = (const float*)d_in[27];
  const float* m1_w2 = (const float*)d_in[28]; const float* m1_b2 = (const float*)d_in[29];
  const float* m2_w1 = (const float*)d_in[30]; const float* m2_b1 = (const float*)d_in[31];
  const float* m2_w2 = (const float*)d_in[32]; const float* m2_b2 = (const float*)d_in[33];

  const int S = 2048, C = 1024, Mh = 4096;
  const size_t CC = (size_t)C * C;
  float* xout = (float*)d_out;

  char* p = (char*)d_ws;
  auto take = [&](size_t bytes) { char* q = p; p += (bytes + 255) & ~(size_t)255; return q; };
  u16* wt_qkv  = (u16*)take(3 * CC * 2);
  u16* wt_sap  = (u16*)take(CC * 2);
  u16* wt_cap  = (u16*)take(CC * 2);
  u16* wt_caq  = (u16*)take(CC * 2);
  u16* wt_ckv  = (u16*)take(2 * CC * 2);
  u16* wt_m1w1 = (u16*)take((size_t)C * Mh * 2);
  u16* wt_m1w2 = (u16*)take((size_t)C * Mh * 2);
  u16* wt_m2w1 = (u16*)take((size_t)C * Mh * 2);
  u16* wt_m2w2 = (u16*)take((size_t)C * Mh * 2);
  float* bias_qkv = (float*)take(3 * C * 4);
  float* bias_ckv = (float*)take(2 * C * 4);
  u16* xn   = (u16*)take((size_t)S * C * 2);
  u16* encb = (u16*)take((size_t)S * C * 2);
  u16* vtbuf = (u16*)take((size_t)C * S * 2);
  u16* abuf  = (u16*)take((size_t)S * C * 2);
  u16* hbuf  = (u16*)take((size_t)S * Mh * 2);
  u16* qkbuf = hbuf;                            // self Q|K packed [S][2048]
  u16* qbuf  = hbuf + (size_t)4 * 1024 * 1024;  // cross Q [S][1024]
  u16* kvbuf = hbuf + (size_t)6 * 1024 * 1024;  // cross K [S][1024]

  dim3 blk(256);
  const float qs2 = 0.125f * 1.4426950408889634f;  // hd^-0.5 * log2(e)
  const int BIG = 1 << 30;

  k_transpose<<<dim3(C / 32, C / 32), blk, 0, stream>>>(sa_qw, wt_qkv, C, C);
  k_transpose<<<dim3(C / 32, C / 32), blk, 0, stream>>>(sa_kw, wt_qkv + CC, C, C);
  k_transpose<<<dim3(C / 32, C / 32), blk, 0, stream>>>(sa_vw, wt_qkv + 2 * CC, C, C);
  k_transpose<<<dim3(C / 32, C / 32), blk, 0, stream>>>(sa_pw, wt_sap, C, C);
  k_transpose<<<dim3(C / 32, C / 32), blk, 0, stream>>>(ca_pw, wt_cap, C, C);
  k_transpose<<<dim3(C / 32, C / 32), blk, 0, stream>>>(ca_qw, wt_caq, C, C);
  k_transpose<<<dim3(C / 32, C / 32), blk, 0, stream>>>(ca_kw, wt_ckv, C, C);
  k_transpose<<<dim3(C / 32, C / 32), blk, 0, stream>>>(ca_vw, wt_ckv + CC, C, C);
  k_transpose<<<dim3(Mh / 32, C / 32), blk, 0, stream>>>(m1_w1, wt_m1w1, C, Mh);
  k_transpose<<<dim3(C / 32, Mh / 32), blk, 0, stream>>>(m1_w2, wt_m1w2, Mh, C);
  k_transpose<<<dim3(Mh / 32, C / 32), blk, 0, stream>>>(m2_w1, wt_m2w1, C, Mh);
  k_transpose<<<dim3(C / 32, Mh / 32), blk, 0, stream>>>(m2_w2, wt_m2w2, Mh, C);
  k_cvt<<<dim3(S * C / 1024), blk, 0, stream>>>(enc, encb, S * C / 4);
  k_copyf<<<4, blk, 0, stream>>>(bias_qkv, sa_qb, C);
  k_copyf<<<4, blk, 0, stream>>>(bias_qkv + C, sa_kb, C);
  k_copyf<<<4, blk, 0, stream>>>(bias_qkv + 2 * C, sa_vb, C);
  k_copyf<<<4, blk, 0, stream>>>(bias_ckv, ca_kb, C);
  k_copyf<<<4, blk, 0, stream>>>(bias_ckv + C, ca_vb, C);

  // --- block 1: self-attention (causal)
  k_ln<<<S, blk, 0, stream>>>(features, g1a, b1a, xn);
  k_gemm<0, 64><<<dim3(24, 32), blk, 0, stream>>>(xn, wt_qkv, bias_qkv, nullptr, qkbuf, vtbuf,
                                                  S, 3072, C, 2048, qs2, 1024, 2048);
  k_attn2<true><<<dim3(16, 16), blk, 0, stream>>>(qkbuf, qkbuf + 1024, vtbuf, abuf, S, 2048, 2048);
  k_gemm<1, 64><<<dim3(8, 32), blk, 0, stream>>>(abuf, wt_sap, sa_pb, features, xout, nullptr,
                                                 S, C, C, C, 1.f, 0, BIG);
  // --- MLP 1
  k_ln<<<S, blk, 0, stream>>>(xout, g1b, b1b, xn);
  k_gemm<2, 128><<<dim3(32, 16), blk, 0, stream>>>(xn, wt_m1w1, m1_b1, nullptr, hbuf, nullptr,
                                                   S, Mh, C, Mh, 1.f, 0, BIG);
  k_gemm<1, 64><<<dim3(8, 32), blk, 0, stream>>>(hbuf, wt_m1w2, m1_b2, xout, xout, nullptr,
                                                 S, C, Mh, C, 1.f, 0, BIG);
  // --- block 2: cross-attention
  k_ln<<<S, blk, 0, stream>>>(xout, g2a, b2a, xn);
  k_gemm<0, 64><<<dim3(8, 32), blk, 0, stream>>>(xn, wt_caq, ca_qb, nullptr, qbuf, nullptr,
                                                 S, C, C, C, qs2, 1024, BIG);
  k_gemm<0, 128><<<dim3(16, 16), blk, 0, stream>>>(encb, wt_ckv, bias_ckv, nullptr, kvbuf, vtbuf,
                                                   S, 2048, C, 1024, 1.f, 0, 1024);
  k_attn2<false><<<dim3(16, 16), blk, 0, stream>>>(qbuf, kvbuf, vtbuf, abuf, S, 1024, 1024);
  k_gemm<1, 64><<<dim3(8, 32), blk, 0, stream>>>(abuf, wt_cap, ca_pb, xout, xout, nullptr,
                                                 S, C, C, C, 1.f, 0, BIG);
  // --- MLP 2
  k_ln<<<S, blk, 0, stream>>>(xout, g2b, b2b, xn);
  k_gemm<2, 128><<<dim3(32, 16), blk, 0, stream>>>(xn, wt_m2w1, m2_b1, nullptr, hbuf, nullptr,
                                                   S, Mh, C, Mh, 1.f, 0, BIG);
  k_gemm<1, 64><<<dim3(8, 32), blk, 0, stream>>>(hbuf, wt_m2w2, m2_b2, xout, xout, nullptr,
                                                 S, C, Mh, C, 1.f, 0, BIG);
}

// Round 5
// 460.819 us; speedup vs baseline: 1.5159x; 1.0861x over previous
//
#include <hip/hip_runtime.h>
#include <math.h>

typedef unsigned short u16;
typedef __bf16 bf16_t;
typedef bf16_t bf16x8 __attribute__((ext_vector_type(8)));
typedef float f32x4 __attribute__((ext_vector_type(4)));
typedef float f32x16 __attribute__((ext_vector_type(16)));

#define DI __device__ __forceinline__

DI u16 f2bf(float f) {
  union { float f; unsigned u; } c; c.f = f;
  unsigned r = c.u + 0x7FFFu + ((c.u >> 16) & 1u);
  return (u16)(r >> 16);
}

DI unsigned pack2(float lo, float hi_) {
  return (unsigned)f2bf(lo) | ((unsigned)f2bf(hi_) << 16);
}

typedef __attribute__((address_space(1))) void* gas_ptr;
typedef __attribute__((address_space(3))) void* las_ptr;

DI void gload16(const void* g, void* l) {
  __builtin_amdgcn_global_load_lds((gas_ptr)g, (las_ptr)l, 16, 0, 0);
}

// ---------------- transpose + convert: w [K][N] f32  ->  wt [N][K] bf16 ----------------
__global__ __launch_bounds__(256) void k_transpose(const float* __restrict__ w,
                                                   u16* __restrict__ wt, int K, int N) {
  __shared__ float tile[32][33];
  int n0 = blockIdx.x * 32, k0 = blockIdx.y * 32;
  int tx = threadIdx.x & 31, ty = threadIdx.x >> 5;
  for (int r = ty; r < 32; r += 8)
    tile[r][tx] = w[(size_t)(k0 + r) * N + n0 + tx];
  __syncthreads();
  for (int r = ty; r < 32; r += 8)
    wt[(size_t)(n0 + r) * K + k0 + tx] = f2bf(tile[tx][r]);
}

// ---------------- f32 -> bf16 elementwise ----------------
__global__ __launch_bounds__(256) void k_cvt(const float* __restrict__ in, u16* __restrict__ out, int n4) {
  int i = blockIdx.x * 256 + threadIdx.x;
  if (i < n4) {
    float4 v = ((const float4*)in)[i];
    ushort4 o;
    o.x = f2bf(v.x); o.y = f2bf(v.y); o.z = f2bf(v.z); o.w = f2bf(v.w);
    ((ushort4*)out)[i] = o;
  }
}

// ---------------- f32 copy (bias packing) ----------------
__global__ __launch_bounds__(256) void k_copyf(float* __restrict__ dst, const float* __restrict__ src, int n) {
  int i = blockIdx.x * 256 + threadIdx.x;
  if (i < n) dst[i] = src[i];
}

// ---------------- LayerNorm over C=1024, fp32 in -> bf16 out ----------------
__global__ __launch_bounds__(256) void k_ln(const float* __restrict__ x, const float* __restrict__ g,
                                            const float* __restrict__ b, u16* __restrict__ out) {
  int row = blockIdx.x, t = threadIdx.x;
  const float4 v = ((const float4*)(x + (size_t)row * 1024))[t];
  float s = v.x + v.y + v.z + v.w;
  float ss = v.x * v.x + v.y * v.y + v.z * v.z + v.w * v.w;
  for (int o = 32; o; o >>= 1) { s += __shfl_down(s, o); ss += __shfl_down(ss, o); }
  __shared__ float red[10];
  int w = t >> 6;
  if ((t & 63) == 0) { red[w] = s; red[4 + w] = ss; }
  __syncthreads();
  if (t == 0) {
    float S = red[0] + red[1] + red[2] + red[3];
    float SS = red[4] + red[5] + red[6] + red[7];
    float mean = S * (1.f / 1024.f);
    float var = SS * (1.f / 1024.f) - mean * mean;
    red[8] = mean; red[9] = rsqrtf(var + 1e-6f);
  }
  __syncthreads();
  float mean = red[8], rstd = red[9];
  float4 gg = ((const float4*)g)[t], bb = ((const float4*)b)[t];
  ushort4 o4;
  o4.x = f2bf((v.x - mean) * rstd * gg.x + bb.x);
  o4.y = f2bf((v.y - mean) * rstd * gg.y + bb.y);
  o4.z = f2bf((v.z - mean) * rstd * gg.z + bb.z);
  o4.w = f2bf((v.w - mean) * rstd * gg.w + bb.w);
  ((ushort4*)(out + (size_t)row * 1024))[t] = o4;
}

// ---------------- GEMM: out[M,N] = A[M,K](bf16) @ Bt[N,K]^T + bias ----------------
// MODE 0: bf16 out (scale cols < scale_end); cols >= vcol0 written TRANSPOSED to vtout.
// MODE 1: f32 out = res + acc + bias.   MODE 2: bf16 out = gelu(acc + bias).
template <int MODE, int BM>
__global__ __launch_bounds__(256) void k_gemm(const u16* __restrict__ A, const u16* __restrict__ Bt,
                                              const float* __restrict__ bias, const float* res,
                                              void* outv, u16* vtout, int M, int N, int K,
                                              int ostride, float scale, int scale_end, int vcol0) {
  constexpr int NT = (BM == 128) ? 4 : 2;
  __shared__ u16 aL[BM * 64];
  __shared__ u16 bL[128 * 64];
  const int lane = threadIdx.x & 63, w = threadIdx.x >> 6, t = threadIdx.x;
  const int wm = (BM == 128) ? (w >> 1) : 0;
  const int wn = (BM == 128) ? (w & 1) : w;
  const int m0 = blockIdx.y * BM, n0 = blockIdx.x * 128;

  f32x4 acc[4][NT];
#pragma unroll
  for (int i = 0; i < 4; ++i)
#pragma unroll
    for (int j = 0; j < NT; ++j) acc[i][j] = (f32x4){0.f, 0.f, 0.f, 0.f};

  const int nkt = K >> 6;
  for (int kt = 0; kt < nkt; ++kt) {
    const int k0 = kt << 6;
#pragma unroll
    for (int c = t; c < BM * 8; c += 256) {
      int row = c >> 3, c16 = c & 7;
      int sw = (c16 * 16) ^ ((row & 7) << 4);
      gload16((const char*)(A + (size_t)(m0 + row) * K + k0) + sw, (char*)aL + c * 16);
    }
#pragma unroll
    for (int c = t; c < 1024; c += 256) {
      int row = c >> 3, c16 = c & 7;
      int sw = (c16 * 16) ^ ((row & 7) << 4);
      gload16((const char*)(Bt + (size_t)(n0 + row) * K + k0) + sw, (char*)bL + c * 16);
    }
    __syncthreads();
#pragma unroll
    for (int kk = 0; kk < 2; ++kk) {
      const int cb = kk * 64 + ((lane >> 4) << 4);
      bf16x8 af[4], bfr[NT];
#pragma unroll
      for (int mi = 0; mi < 4; ++mi) {
        int row = wm * 64 + mi * 16 + (lane & 15);
        af[mi] = *(const bf16x8*)((const char*)aL + row * 128 + (cb ^ ((row & 7) << 4)));
      }
#pragma unroll
      for (int ni = 0; ni < NT; ++ni) {
        int row = wn * (NT * 16) + ni * 16 + (lane & 15);
        bfr[ni] = *(const bf16x8*)((const char*)bL + row * 128 + (cb ^ ((row & 7) << 4)));
      }
#pragma unroll
      for (int mi = 0; mi < 4; ++mi)
#pragma unroll
        for (int ni = 0; ni < NT; ++ni)
          acc[mi][ni] = __builtin_amdgcn_mfma_f32_16x16x32_bf16(af[mi], bfr[ni], acc[mi][ni], 0, 0, 0);
    }
    __syncthreads();
  }

  const int cBase = n0 + wn * (NT * 16) + (lane & 15);
  const int rBase = m0 + wm * 64 + ((lane >> 4) << 2);
#pragma unroll
  for (int ni = 0; ni < NT; ++ni) {
    int col = cBase + ni * 16;
    float bv = bias[col];
#pragma unroll
    for (int mi = 0; mi < 4; ++mi) {
      int row = rBase + mi * 16;
      f32x4 a = acc[mi][ni];
      if (MODE == 0) {
        float sc = (col < scale_end) ? scale : 1.f;
        if (col >= vcol0) {
          ushort4 o4;
          o4.x = f2bf((a[0] + bv) * sc); o4.y = f2bf((a[1] + bv) * sc);
          o4.z = f2bf((a[2] + bv) * sc); o4.w = f2bf((a[3] + bv) * sc);
          *(ushort4*)(vtout + (size_t)(col - vcol0) * M + row) = o4;
        } else {
#pragma unroll
          for (int r = 0; r < 4; ++r)
            ((u16*)outv)[(size_t)(row + r) * ostride + col] = f2bf((a[r] + bv) * sc);
        }
      } else if (MODE == 1) {
#pragma unroll
        for (int r = 0; r < 4; ++r) {
          size_t idx = (size_t)(row + r) * ostride + col;
          ((float*)outv)[idx] = res[idx] + a[r] + bv;
        }
      } else {
#pragma unroll
        for (int r = 0; r < 4; ++r) {
          float v = a[r] + bv;
          ((u16*)outv)[(size_t)(row + r) * ostride + col] =
              f2bf(0.5f * v * (1.f + erff(v * 0.70710678118654752f)));
        }
      }
    }
  }
}

// ---------------- flash attention, split-KV x4 in-block, swapped 32x32 ----------------
// Q [S][qstride] (pre-scaled by hd^-0.5*log2e), K [S][kstride], VT [1024][S], O [S][1024].
// Block: 512 threads = 8 waves = 2 q-waves (32 rows, QBLK=64) x 4 KV-splits.
// LDS: 4 x 16KB private K/V staging | merge reuses it | +2KB m,l | +8KB O-tile.
template <bool CAUSAL>
__global__ __launch_bounds__(512, 4) void k_attn3(const u16* __restrict__ Q, const u16* __restrict__ K,
                                                  const u16* __restrict__ VT, u16* __restrict__ O,
                                                  int S, int qstride, int kstride) {
  __shared__ __align__(16) char smem[64 * 1024 + 2048 + 8192];
  const int t = threadIdx.x, lane = t & 63, w = t >> 6;   // w 0..7
  const int ks = w & 3, qw = w >> 2;                      // split 0..3, q-wave 0..1
  const int lo5 = lane & 31, hi = lane >> 5;
  const int h = blockIdx.x;
  const int bq = blockIdx.y;
  const int qt = (bq < 16) ? bq : 47 - bq;                // causal pairing: qt + (31-qt) co-resident
  const int hd0 = h * 64;
  const int q0 = qt * 64 + qw * 32;
  const int ts = qw * 64 + lane;                          // 0..127 within split

  u16* kL = (u16*)(smem + ks * 16384);
  u16* vL = (u16*)(smem + ks * 16384 + 8192);

  // Q fragments (B-operand): col=q=lane&31, k(d-local) = sl*16 + hi*8 + e
  bf16x8 qf[4];
#pragma unroll
  for (int sl = 0; sl < 4; ++sl)
    qf[sl] = *(const bf16x8*)(Q + (size_t)(q0 + lo5) * qstride + hd0 + sl * 16 + hi * 8);

  f32x16 oa0 = {}, oa1 = {};  // O^T: d rows [0..31],[32..63], col q = lane&31
  float mrun = -1e30f, lsum = 0.f;

  const int nkt = CAUSAL ? (qt + 1) : (S >> 6);
  const int nIter = (nkt + 3) >> 2;

  for (int i = 0; i < nIter; ++i) {
    const int kt = ks + 4 * i;
    const bool active = kt < nkt;
    if (active) {
#pragma unroll
      for (int j = 0; j < 4; ++j) {
        int c = j * 128 + ts, row = c >> 3, c16 = c & 7;
        int sw = (c16 * 16) ^ ((row & 7) << 4);
        gload16((const char*)(K + (size_t)(kt * 64 + row) * kstride + hd0) + sw, (char*)kL + c * 16);
      }
#pragma unroll
      for (int j = 0; j < 4; ++j) {
        int c = j * 128 + ts, row = c >> 3, c16 = c & 7;
        int sw = (c16 * 16) ^ ((row & 7) << 4);
        gload16((const char*)(VT + (size_t)(hd0 + row) * S + kt * 64) + sw, (char*)vL + c * 16);
      }
    }
    __syncthreads();
    if (active) {
      // S^T[kv][q] = K · Q^T
      f32x16 s0 = {}, s1 = {};
#pragma unroll
      for (int sl = 0; sl < 4; ++sl) {
        int cb = sl * 32 + hi * 16;
        int r0 = lo5, r1 = 32 + lo5;
        bf16x8 kf0 = *(const bf16x8*)((const char*)kL + r0 * 128 + (cb ^ ((r0 & 7) << 4)));
        bf16x8 kf1 = *(const bf16x8*)((const char*)kL + r1 * 128 + (cb ^ ((r1 & 7) << 4)));
        s0 = __builtin_amdgcn_mfma_f32_32x32x16_bf16(kf0, qf[sl], s0, 0, 0, 0);
        s1 = __builtin_amdgcn_mfma_f32_32x32x16_bf16(kf1, qf[sl], s1, 0, 0, 0);
      }

      if (CAUSAL && kt == qt) {
        int qg = q0 + lo5;
#pragma unroll
        for (int r = 0; r < 16; ++r) {
          int kg = kt * 64 + (r & 3) + 8 * (r >> 2) + 4 * hi;
          if (kg > qg) s0[r] = -1e30f;
          if (kg + 32 > qg) s1[r] = -1e30f;
        }
      }

      float pm = s0[0];
#pragma unroll
      for (int r = 1; r < 16; ++r) pm = fmaxf(pm, s0[r]);
#pragma unroll
      for (int r = 0; r < 16; ++r) pm = fmaxf(pm, s1[r]);
      pm = fmaxf(pm, __shfl_xor(pm, 32));

      float mnew = fmaxf(mrun, pm);
      float sc = exp2f(mrun - mnew);
      lsum *= sc;
#pragma unroll
      for (int r = 0; r < 16; ++r) { oa0[r] *= sc; oa1[r] *= sc; }
      mrun = mnew;

      float ps = 0.f;
#pragma unroll
      for (int r = 0; r < 16; ++r) { s0[r] = exp2f(s0[r] - mrun); ps += s0[r]; }
#pragma unroll
      for (int r = 0; r < 16; ++r) { s1[r] = exp2f(s1[r] - mrun); ps += s1[r]; }
      ps += __shfl_xor(ps, 32);
      lsum += ps;

#pragma unroll
      for (int ksl = 0; ksl < 4; ++ksl) {
        const int base = 8 * (ksl & 1);
        float pA0, pA1, pA2, pA3, pB0, pB1, pB2, pB3;
        if (ksl < 2) {
          pA0 = s0[base + 0]; pA1 = s0[base + 1]; pA2 = s0[base + 2]; pA3 = s0[base + 3];
          pB0 = s0[base + 4]; pB1 = s0[base + 5]; pB2 = s0[base + 6]; pB3 = s0[base + 7];
        } else {
          pA0 = s1[base + 0]; pA1 = s1[base + 1]; pA2 = s1[base + 2]; pA3 = s1[base + 3];
          pB0 = s1[base + 4]; pB1 = s1[base + 5]; pB2 = s1[base + 6]; pB3 = s1[base + 7];
        }
        unsigned a01 = pack2(pA0, pA1), a23 = pack2(pA2, pA3);
        unsigned b01 = pack2(pB0, pB1), b23 = pack2(pB2, pB3);
        unsigned xa01 = __shfl_xor(a01, 32), xa23 = __shfl_xor(a23, 32);
        unsigned xb01 = __shfl_xor(b01, 32), xb23 = __shfl_xor(b23, 32);
        union { unsigned u[4]; bf16x8 v; } pf;
        pf.u[0] = hi ? xb01 : a01;
        pf.u[1] = hi ? xb23 : a23;
        pf.u[2] = hi ? b01 : xa01;
        pf.u[3] = hi ? b23 : xa23;
        int cb = ksl * 32 + hi * 16;
        int r0 = lo5, r1 = 32 + lo5;
        bf16x8 vf0 = *(const bf16x8*)((const char*)vL + r0 * 128 + (cb ^ ((r0 & 7) << 4)));
        bf16x8 vf1 = *(const bf16x8*)((const char*)vL + r1 * 128 + (cb ^ ((r1 & 7) << 4)));
        oa0 = __builtin_amdgcn_mfma_f32_32x32x16_bf16(vf0, pf.v, oa0, 0, 0, 0);
        oa1 = __builtin_amdgcn_mfma_f32_32x32x16_bf16(vf1, pf.v, oa1, 0, 0, 0);
      }
    }
    __syncthreads();
  }

  // ---- merge across splits (tree: ks{2,3}->ks{0,1}, then ks1->ks0) ----
  float* mlBuf = (float*)(smem + 65536);
#define OB_BYTE(g, halfoff) (lo5 * 256 + (((halfoff) + 32 * (g) + 16 * hi) ^ ((lo5 & 15) << 4)))
  if (ks >= 2) {
    char* ob = smem + (qw * 2 + (ks - 2)) * 8192;
#pragma unroll
    for (int g = 0; g < 4; ++g) {
      float4 f0 = make_float4(oa0[4 * g + 0], oa0[4 * g + 1], oa0[4 * g + 2], oa0[4 * g + 3]);
      *(float4*)(ob + OB_BYTE(g, 0)) = f0;
      float4 f1 = make_float4(oa1[4 * g + 0], oa1[4 * g + 1], oa1[4 * g + 2], oa1[4 * g + 3]);
      *(float4*)(ob + OB_BYTE(g, 128)) = f1;
    }
    if (hi == 0) { mlBuf[(w * 32 + lo5) * 2] = mrun; mlBuf[(w * 32 + lo5) * 2 + 1] = lsum; }
  }
  __syncthreads();
  if (ks < 2) {
    int pw = qw * 4 + ks + 2;
    char* ob = smem + (qw * 2 + ks) * 8192;
    float mB = mlBuf[(pw * 32 + lo5) * 2], lB = mlBuf[(pw * 32 + lo5) * 2 + 1];
    float M = fmaxf(mrun, mB);
    float sA = exp2f(mrun - M), sB = exp2f(mB - M);
    lsum = lsum * sA + lB * sB;
    mrun = M;
#pragma unroll
    for (int g = 0; g < 4; ++g) {
      float4 v0 = *(const float4*)(ob + OB_BYTE(g, 0));
      float4 v1 = *(const float4*)(ob + OB_BYTE(g, 128));
      oa0[4 * g + 0] = oa0[4 * g + 0] * sA + v0.x * sB;
      oa0[4 * g + 1] = oa0[4 * g + 1] * sA + v0.y * sB;
      oa0[4 * g + 2] = oa0[4 * g + 2] * sA + v0.z * sB;
      oa0[4 * g + 3] = oa0[4 * g + 3] * sA + v0.w * sB;
      oa1[4 * g + 0] = oa1[4 * g + 0] * sA + v1.x * sB;
      oa1[4 * g + 1] = oa1[4 * g + 1] * sA + v1.y * sB;
      oa1[4 * g + 2] = oa1[4 * g + 2] * sA + v1.z * sB;
      oa1[4 * g + 3] = oa1[4 * g + 3] * sA + v1.w * sB;
    }
  }
  if (ks == 1) {
    char* ob = smem + 32768 + qw * 8192;
#pragma unroll
    for (int g = 0; g < 4; ++g) {
      float4 f0 = make_float4(oa0[4 * g + 0], oa0[4 * g + 1], oa0[4 * g + 2], oa0[4 * g + 3]);
      *(float4*)(ob + OB_BYTE(g, 0)) = f0;
      float4 f1 = make_float4(oa1[4 * g + 0], oa1[4 * g + 1], oa1[4 * g + 2], oa1[4 * g + 3]);
      *(float4*)(ob + OB_BYTE(g, 128)) = f1;
    }
    if (hi == 0) { mlBuf[(w * 32 + lo5) * 2] = mrun; mlBuf[(w * 32 + lo5) * 2 + 1] = lsum; }
  }
  __syncthreads();
  if (ks == 0) {
    int pw = qw * 4 + 1;
    char* ob = smem + 32768 + qw * 8192;
    float mB = mlBuf[(pw * 32 + lo5) * 2], lB = mlBuf[(pw * 32 + lo5) * 2 + 1];
    float M = fmaxf(mrun, mB);
    float sA = exp2f(mrun - M), sB = exp2f(mB - M);
    lsum = lsum * sA + lB * sB;
#pragma unroll
    for (int g = 0; g < 4; ++g) {
      float4 v0 = *(const float4*)(ob + OB_BYTE(g, 0));
      float4 v1 = *(const float4*)(ob + OB_BYTE(g, 128));
      oa0[4 * g + 0] = oa0[4 * g + 0] * sA + v0.x * sB;
      oa0[4 * g + 1] = oa0[4 * g + 1] * sA + v0.y * sB;
      oa0[4 * g + 2] = oa0[4 * g + 2] * sA + v0.z * sB;
      oa0[4 * g + 3] = oa0[4 * g + 3] * sA + v0.w * sB;
      oa1[4 * g + 0] = oa1[4 * g + 0] * sA + v1.x * sB;
      oa1[4 * g + 1] = oa1[4 * g + 1] * sA + v1.y * sB;
      oa1[4 * g + 2] = oa1[4 * g + 2] * sA + v1.z * sB;
      oa1[4 * g + 3] = oa1[4 * g + 3] * sA + v1.w * sB;
    }
    // pack to O-tile LDS [64 q][64 d] bf16 swizzled
    float inv = 1.f / lsum;
    u16* ldsO = (u16*)(smem + 65536 + 2048);
    int qrow = qw * 32 + lo5;
#pragma unroll
    for (int g = 0; g < 4; ++g) {
      unsigned w0 = pack2(oa0[4 * g + 0] * inv, oa0[4 * g + 1] * inv);
      unsigned w1 = pack2(oa0[4 * g + 2] * inv, oa0[4 * g + 3] * inv);
      int dby = (8 * g + 4 * hi) * 2;
      *(uint2*)((char*)ldsO + qrow * 128 + (dby ^ ((qrow & 7) << 4))) = make_uint2(w0, w1);
      unsigned w2 = pack2(oa1[4 * g + 0] * inv, oa1[4 * g + 1] * inv);
      unsigned w3 = pack2(oa1[4 * g + 2] * inv, oa1[4 * g + 3] * inv);
      int dby2 = (32 + 8 * g + 4 * hi) * 2;
      *(uint2*)((char*)ldsO + qrow * 128 + (dby2 ^ ((qrow & 7) << 4))) = make_uint2(w2, w3);
    }
  }
  __syncthreads();
  {
    u16* ldsO = (u16*)(smem + 65536 + 2048);
    int c = t, row = c >> 3, c16 = c & 7;  // 512 threads = 64 rows x 8 chunks
    uint4 val = *(const uint4*)((const char*)ldsO + row * 128 + ((c16 * 16) ^ ((row & 7) << 4)));
    *(uint4*)(O + (size_t)(qt * 64 + row) * 1024 + hd0 + c16 * 8) = val;
  }
#undef OB_BYTE
}

// ==========================================================================================
extern "C" void kernel_launch(void* const* d_in, const int* in_sizes, int n_in,
                              void* d_out, int out_size, void* d_ws, size_t ws_size,
                              hipStream_t stream) {
  const float* features = (const float*)d_in[0];
  const float* enc      = (const float*)d_in[1];
  const float* g1a = (const float*)d_in[2];  const float* b1a = (const float*)d_in[3];
  const float* g1b = (const float*)d_in[4];  const float* b1b = (const float*)d_in[5];
  const float* g2a = (const float*)d_in[6];  const float* b2a = (const float*)d_in[7];
  const float* g2b = (const float*)d_in[8];  const float* b2b = (const float*)d_in[9];
  const float* sa_qw = (const float*)d_in[10]; const float* sa_qb = (const float*)d_in[11];
  const float* sa_kw = (const float*)d_in[12]; const float* sa_kb = (const float*)d_in[13];
  const float* sa_vw = (const float*)d_in[14]; const float* sa_vb = (const float*)d_in[15];
  const float* sa_pw = (const float*)d_in[16]; const float* sa_pb = (const float*)d_in[17];
  const float* ca_qw = (const float*)d_in[18]; const float* ca_qb = (const float*)d_in[19];
  const float* ca_kw = (const float*)d_in[20]; const float* ca_kb = (const float*)d_in[21];
  const float* ca_vw = (const float*)d_in[22]; const float* ca_vb = (const float*)d_in[23];
  const float* ca_pw = (const float*)d_in[24]; const float* ca_pb = (const float*)d_in[25];
  const float* m1_w1 = (const float*)d_in[26]; const float* m1_b1 = (const float*)d_in[27];
  const float* m1_w2 = (const float*)d_in[28]; const float* m1_b2 = (const float*)d_in[29];
  const float* m2_w1 = (const float*)d_in[30]; const float* m2_b1 = (const float*)d_in[31];
  const float* m2_w2 = (const float*)d_in[32]; const float* m2_b2 = (const float*)d_in[33];

  const int S = 2048, C = 1024, Mh = 4096;
  const size_t CC = (size_t)C * C;
  float* xout = (float*)d_out;

  char* p = (char*)d_ws;
  auto take = [&](size_t bytes) { char* q = p; p += (bytes + 255) & ~(size_t)255; return q; };
  u16* wt_qkv  = (u16*)take(3 * CC * 2);
  u16* wt_sap  = (u16*)take(CC * 2);
  u16* wt_cap  = (u16*)take(CC * 2);
  u16* wt_caq  = (u16*)take(CC * 2);
  u16* wt_ckv  = (u16*)take(2 * CC * 2);
  u16* wt_m1w1 = (u16*)take((size_t)C * Mh * 2);
  u16* wt_m1w2 = (u16*)take((size_t)C * Mh * 2);
  u16* wt_m2w1 = (u16*)take((size_t)C * Mh * 2);
  u16* wt_m2w2 = (u16*)take((size_t)C * Mh * 2);
  float* bias_qkv = (float*)take(3 * C * 4);
  float* bias_ckv = (float*)take(2 * C * 4);
  u16* xn   = (u16*)take((size_t)S * C * 2);
  u16* encb = (u16*)take((size_t)S * C * 2);
  u16* vtbuf = (u16*)take((size_t)C * S * 2);
  u16* abuf  = (u16*)take((size_t)S * C * 2);
  u16* hbuf  = (u16*)take((size_t)S * Mh * 2);
  u16* qkbuf = hbuf;                            // self Q|K packed [S][2048]
  u16* qbuf  = hbuf + (size_t)4 * 1024 * 1024;  // cross Q [S][1024]
  u16* kvbuf = hbuf + (size_t)6 * 1024 * 1024;  // cross K [S][1024]

  dim3 blk(256);
  const float qs2 = 0.125f * 1.4426950408889634f;  // hd^-0.5 * log2(e)
  const int BIG = 1 << 30;

  k_transpose<<<dim3(C / 32, C / 32), blk, 0, stream>>>(sa_qw, wt_qkv, C, C);
  k_transpose<<<dim3(C / 32, C / 32), blk, 0, stream>>>(sa_kw, wt_qkv + CC, C, C);
  k_transpose<<<dim3(C / 32, C / 32), blk, 0, stream>>>(sa_vw, wt_qkv + 2 * CC, C, C);
  k_transpose<<<dim3(C / 32, C / 32), blk, 0, stream>>>(sa_pw, wt_sap, C, C);
  k_transpose<<<dim3(C / 32, C / 32), blk, 0, stream>>>(ca_pw, wt_cap, C, C);
  k_transpose<<<dim3(C / 32, C / 32), blk, 0, stream>>>(ca_qw, wt_caq, C, C);
  k_transpose<<<dim3(C / 32, C / 32), blk, 0, stream>>>(ca_kw, wt_ckv, C, C);
  k_transpose<<<dim3(C / 32, C / 32), blk, 0, stream>>>(ca_vw, wt_ckv + CC, C, C);
  k_transpose<<<dim3(Mh / 32, C / 32), blk, 0, stream>>>(m1_w1, wt_m1w1, C, Mh);
  k_transpose<<<dim3(C / 32, Mh / 32), blk, 0, stream>>>(m1_w2, wt_m1w2, Mh, C);
  k_transpose<<<dim3(Mh / 32, C / 32), blk, 0, stream>>>(m2_w1, wt_m2w1, C, Mh);
  k_transpose<<<dim3(C / 32, Mh / 32), blk, 0, stream>>>(m2_w2, wt_m2w2, Mh, C);
  k_cvt<<<dim3(S * C / 1024), blk, 0, stream>>>(enc, encb, S * C / 4);
  k_copyf<<<4, blk, 0, stream>>>(bias_qkv, sa_qb, C);
  k_copyf<<<4, blk, 0, stream>>>(bias_qkv + C, sa_kb, C);
  k_copyf<<<4, blk, 0, stream>>>(bias_qkv + 2 * C, sa_vb, C);
  k_copyf<<<4, blk, 0, stream>>>(bias_ckv, ca_kb, C);
  k_copyf<<<4, blk, 0, stream>>>(bias_ckv + C, ca_vb, C);

  // --- block 1: self-attention (causal)
  k_ln<<<S, blk, 0, stream>>>(features, g1a, b1a, xn);
  k_gemm<0, 64><<<dim3(24, 32), blk, 0, stream>>>(xn, wt_qkv, bias_qkv, nullptr, qkbuf, vtbuf,
                                                  S, 3072, C, 2048, qs2, 1024, 2048);
  k_attn3<true><<<dim3(16, 32), dim3(512), 0, stream>>>(qkbuf, qkbuf + 1024, vtbuf, abuf, S, 2048, 2048);
  k_gemm<1, 64><<<dim3(8, 32), blk, 0, stream>>>(abuf, wt_sap, sa_pb, features, xout, nullptr,
                                                 S, C, C, C, 1.f, 0, BIG);
  // --- MLP 1
  k_ln<<<S, blk, 0, stream>>>(xout, g1b, b1b, xn);
  k_gemm<2, 128><<<dim3(32, 16), blk, 0, stream>>>(xn, wt_m1w1, m1_b1, nullptr, hbuf, nullptr,
                                                   S, Mh, C, Mh, 1.f, 0, BIG);
  k_gemm<1, 64><<<dim3(8, 32), blk, 0, stream>>>(hbuf, wt_m1w2, m1_b2, xout, xout, nullptr,
                                                 S, C, Mh, C, 1.f, 0, BIG);
  // --- block 2: cross-attention
  k_ln<<<S, blk, 0, stream>>>(xout, g2a, b2a, xn);
  k_gemm<0, 64><<<dim3(8, 32), blk, 0, stream>>>(xn, wt_caq, ca_qb, nullptr, qbuf, nullptr,
                                                 S, C, C, C, qs2, 1024, BIG);
  k_gemm<0, 128><<<dim3(16, 16), blk, 0, stream>>>(encb, wt_ckv, bias_ckv, nullptr, kvbuf, vtbuf,
                                                   S, 2048, C, 1024, 1.f, 0, 1024);
  k_attn3<false><<<dim3(16, 32), dim3(512), 0, stream>>>(qbuf, kvbuf, vtbuf, abuf, S, 1024, 1024);
  k_gemm<1, 64><<<dim3(8, 32), blk, 0, stream>>>(abuf, wt_cap, ca_pb, xout, xout, nullptr,
                                                 S, C, C, C, 1.f, 0, BIG);
  // --- MLP 2
  k_ln<<<S, blk, 0, stream>>>(xout, g2b, b2b, xn);
  k_gemm<2, 128><<<dim3(32, 16), blk, 0, stream>>>(xn, wt_m2w1, m2_b1, nullptr, hbuf, nullptr,
                                                   S, Mh, C, Mh, 1.f, 0, BIG);
  k_gemm<1, 64><<<dim3(8, 32), blk, 0, stream>>>(hbuf, wt_m2w2, m2_b2, xout, xout, nullptr,
                                                 S, C, Mh, C, 1.f, 0, BIG);
}

// Round 6
// 439.874 us; speedup vs baseline: 1.5880x; 1.0476x over previous
//
#include <hip/hip_runtime.h>
#include <math.h>

typedef unsigned short u16;
typedef __bf16 bf16_t;
typedef bf16_t bf16x8 __attribute__((ext_vector_type(8)));
typedef float f32x4 __attribute__((ext_vector_type(4)));
typedef float f32x16 __attribute__((ext_vector_type(16)));

#define DI __device__ __forceinline__

DI u16 f2bf(float f) {
  union { float f; unsigned u; } c; c.f = f;
  unsigned r = c.u + 0x7FFFu + ((c.u >> 16) & 1u);
  return (u16)(r >> 16);
}

DI unsigned pack2(float lo, float hi_) {
  return (unsigned)f2bf(lo) | ((unsigned)f2bf(hi_) << 16);
}

typedef __attribute__((address_space(1))) void* gas_ptr;
typedef __attribute__((address_space(3))) void* las_ptr;

DI void gload16(const void* g, void* l) {
  __builtin_amdgcn_global_load_lds((gas_ptr)g, (las_ptr)l, 16, 0, 0);
}

// ---------------- fused transpose+convert of all 12 weights ----------------
// w [K][N] f32 -> wt [N][K] bf16.  z<8: 1024x1024; z=8,10: K=1024,N=4096; z=9,11: K=4096,N=1024.
struct TransArgs { const float* src[12]; u16* dst[12]; };
__global__ __launch_bounds__(256) void k_transpose_all(TransArgs ta) {
  __shared__ float tile[32][33];
  int bx = blockIdx.x;
  int z, local, K, N;
  if (bx < 8192) { z = bx >> 10; local = bx & 1023; K = 1024; N = 1024; }
  else {
    int i = bx - 8192; z = 8 + (i >> 12); local = i & 4095;
    if (z & 1) { K = 4096; N = 1024; } else { K = 1024; N = 4096; }
  }
  const float* w = ta.src[z];
  u16* wt = ta.dst[z];
  int nT = N >> 5;
  int n0 = (local % nT) * 32, k0 = (local / nT) * 32;
  int tx = threadIdx.x & 31, ty = threadIdx.x >> 5;
  for (int r = ty; r < 32; r += 8)
    tile[r][tx] = w[(size_t)(k0 + r) * N + n0 + tx];
  __syncthreads();
  for (int r = ty; r < 32; r += 8)
    wt[(size_t)(n0 + r) * K + k0 + tx] = f2bf(tile[tx][r]);
}

// ---------------- f32 -> bf16 elementwise ----------------
__global__ __launch_bounds__(256) void k_cvt(const float* __restrict__ in, u16* __restrict__ out, int n4) {
  int i = blockIdx.x * 256 + threadIdx.x;
  if (i < n4) {
    float4 v = ((const float4*)in)[i];
    ushort4 o;
    o.x = f2bf(v.x); o.y = f2bf(v.y); o.z = f2bf(v.z); o.w = f2bf(v.w);
    ((ushort4*)out)[i] = o;
  }
}

// ---------------- bias packing (5 x 1024 f32 copies in one launch) ----------------
__global__ __launch_bounds__(256) void k_biaspack(float* __restrict__ bq, float* __restrict__ bc,
                                                  const float* qb, const float* kb, const float* vb,
                                                  const float* ckb, const float* cvb) {
  int i = blockIdx.x * 256 + threadIdx.x;
  if (i < 1024) bq[i] = qb[i];
  else if (i < 2048) bq[i] = kb[i - 1024];
  else if (i < 3072) bq[i] = vb[i - 2048];
  else if (i < 4096) bc[i - 3072] = ckb[i - 3072];
  else if (i < 5120) bc[i - 3072] = cvb[i - 4096];
}

// ---------------- LayerNorm over C=1024, fp32 in -> bf16 out ----------------
__global__ __launch_bounds__(256) void k_ln(const float* __restrict__ x, const float* __restrict__ g,
                                            const float* __restrict__ b, u16* __restrict__ out) {
  int row = blockIdx.x, t = threadIdx.x;
  const float4 v = ((const float4*)(x + (size_t)row * 1024))[t];
  float s = v.x + v.y + v.z + v.w;
  float ss = v.x * v.x + v.y * v.y + v.z * v.z + v.w * v.w;
  for (int o = 32; o; o >>= 1) { s += __shfl_down(s, o); ss += __shfl_down(ss, o); }
  __shared__ float red[10];
  int w = t >> 6;
  if ((t & 63) == 0) { red[w] = s; red[4 + w] = ss; }
  __syncthreads();
  if (t == 0) {
    float S = red[0] + red[1] + red[2] + red[3];
    float SS = red[4] + red[5] + red[6] + red[7];
    float mean = S * (1.f / 1024.f);
    float var = SS * (1.f / 1024.f) - mean * mean;
    red[8] = mean; red[9] = rsqrtf(var + 1e-6f);
  }
  __syncthreads();
  float mean = red[8], rstd = red[9];
  float4 gg = ((const float4*)g)[t], bb = ((const float4*)b)[t];
  ushort4 o4;
  o4.x = f2bf((v.x - mean) * rstd * gg.x + bb.x);
  o4.y = f2bf((v.y - mean) * rstd * gg.y + bb.y);
  o4.z = f2bf((v.z - mean) * rstd * gg.z + bb.z);
  o4.w = f2bf((v.w - mean) * rstd * gg.w + bb.w);
  ((ushort4*)(out + (size_t)row * 1024))[t] = o4;
}

// ---------------- GEMM: out[M,N] = A[M,K](bf16) @ Bt[N,K]^T + bias ----------------
// Double-buffered prefetch (T3 minimum 2-phase): stage kt+1 before computing kt.
// MODE 0: bf16 out (scale cols < scale_end); cols >= vcol0 written TRANSPOSED to vtout.
// MODE 1: f32 out = res + acc + bias.   MODE 2: bf16 out = gelu(acc + bias).
template <int MODE, int BM>
__global__ __launch_bounds__(256) void k_gemm(const u16* __restrict__ A, const u16* __restrict__ Bt,
                                              const float* __restrict__ bias, const float* res,
                                              void* outv, u16* vtout, int M, int N, int K,
                                              int ostride, float scale, int scale_end, int vcol0) {
  constexpr int NT = (BM == 128) ? 4 : 2;
  __shared__ u16 aL[2][BM * 64];
  __shared__ u16 bL[2][128 * 64];
  const int lane = threadIdx.x & 63, w = threadIdx.x >> 6, t = threadIdx.x;
  const int wm = (BM == 128) ? (w >> 1) : 0;
  const int wn = (BM == 128) ? (w & 1) : w;
  const int m0 = blockIdx.y * BM, n0 = blockIdx.x * 128;

  f32x4 acc[4][NT];
#pragma unroll
  for (int i = 0; i < 4; ++i)
#pragma unroll
    for (int j = 0; j < NT; ++j) acc[i][j] = (f32x4){0.f, 0.f, 0.f, 0.f};

  auto stage = [&](int buf, int kt) {
    const int k0 = kt << 6;
#pragma unroll
    for (int c = t; c < BM * 8; c += 256) {
      int row = c >> 3, c16 = c & 7;
      int sw = (c16 * 16) ^ ((row & 7) << 4);
      gload16((const char*)(A + (size_t)(m0 + row) * K + k0) + sw, (char*)aL[buf] + c * 16);
    }
#pragma unroll
    for (int c = t; c < 1024; c += 256) {
      int row = c >> 3, c16 = c & 7;
      int sw = (c16 * 16) ^ ((row & 7) << 4);
      gload16((const char*)(Bt + (size_t)(n0 + row) * K + k0) + sw, (char*)bL[buf] + c * 16);
    }
  };

  const int nkt = K >> 6;
  stage(0, 0);
  __syncthreads();
  int cur = 0;
  for (int kt = 0; kt < nkt; ++kt) {
    if (kt + 1 < nkt) stage(cur ^ 1, kt + 1);   // prefetch next tile (hidden under compute)
#pragma unroll
    for (int kk = 0; kk < 2; ++kk) {
      const int cb = kk * 64 + ((lane >> 4) << 4);
      bf16x8 af[4], bfr[NT];
#pragma unroll
      for (int mi = 0; mi < 4; ++mi) {
        int row = wm * 64 + mi * 16 + (lane & 15);
        af[mi] = *(const bf16x8*)((const char*)aL[cur] + row * 128 + (cb ^ ((row & 7) << 4)));
      }
#pragma unroll
      for (int ni = 0; ni < NT; ++ni) {
        int row = wn * (NT * 16) + ni * 16 + (lane & 15);
        bfr[ni] = *(const bf16x8*)((const char*)bL[cur] + row * 128 + (cb ^ ((row & 7) << 4)));
      }
#pragma unroll
      for (int mi = 0; mi < 4; ++mi)
#pragma unroll
        for (int ni = 0; ni < NT; ++ni)
          acc[mi][ni] = __builtin_amdgcn_mfma_f32_16x16x32_bf16(af[mi], bfr[ni], acc[mi][ni], 0, 0, 0);
    }
    __syncthreads();   // drains prefetch loads + joins reads of buf[cur]
    cur ^= 1;
  }

  const int cBase = n0 + wn * (NT * 16) + (lane & 15);
  const int rBase = m0 + wm * 64 + ((lane >> 4) << 2);
#pragma unroll
  for (int ni = 0; ni < NT; ++ni) {
    int col = cBase + ni * 16;
    float bv = bias[col];
#pragma unroll
    for (int mi = 0; mi < 4; ++mi) {
      int row = rBase + mi * 16;
      f32x4 a = acc[mi][ni];
      if (MODE == 0) {
        float sc = (col < scale_end) ? scale : 1.f;
        if (col >= vcol0) {
          ushort4 o4;
          o4.x = f2bf((a[0] + bv) * sc); o4.y = f2bf((a[1] + bv) * sc);
          o4.z = f2bf((a[2] + bv) * sc); o4.w = f2bf((a[3] + bv) * sc);
          *(ushort4*)(vtout + (size_t)(col - vcol0) * M + row) = o4;
        } else {
#pragma unroll
          for (int r = 0; r < 4; ++r)
            ((u16*)outv)[(size_t)(row + r) * ostride + col] = f2bf((a[r] + bv) * sc);
        }
      } else if (MODE == 1) {
#pragma unroll
        for (int r = 0; r < 4; ++r) {
          size_t idx = (size_t)(row + r) * ostride + col;
          ((float*)outv)[idx] = res[idx] + a[r] + bv;
        }
      } else {
#pragma unroll
        for (int r = 0; r < 4; ++r) {
          float v = a[r] + bv;
          ((u16*)outv)[(size_t)(row + r) * ostride + col] =
              f2bf(0.5f * v * (1.f + erff(v * 0.70710678118654752f)));
        }
      }
    }
  }
}

// ---------------- flash attention, split-KV x4 in-block, swapped 32x32 ----------------
template <bool CAUSAL>
__global__ __launch_bounds__(512, 4) void k_attn3(const u16* __restrict__ Q, const u16* __restrict__ K,
                                                  const u16* __restrict__ VT, u16* __restrict__ O,
                                                  int S, int qstride, int kstride) {
  __shared__ __align__(16) char smem[64 * 1024 + 2048 + 8192];
  const int t = threadIdx.x, lane = t & 63, w = t >> 6;   // w 0..7
  const int ks = w & 3, qw = w >> 2;                      // split 0..3, q-wave 0..1
  const int lo5 = lane & 31, hi = lane >> 5;
  const int h = blockIdx.x;
  const int bq = blockIdx.y;
  const int qt = (bq < 16) ? bq : 47 - bq;                // causal pairing
  const int hd0 = h * 64;
  const int q0 = qt * 64 + qw * 32;
  const int ts = qw * 64 + lane;                          // 0..127 within split

  u16* kL = (u16*)(smem + ks * 16384);
  u16* vL = (u16*)(smem + ks * 16384 + 8192);

  bf16x8 qf[4];
#pragma unroll
  for (int sl = 0; sl < 4; ++sl)
    qf[sl] = *(const bf16x8*)(Q + (size_t)(q0 + lo5) * qstride + hd0 + sl * 16 + hi * 8);

  f32x16 oa0 = {}, oa1 = {};
  float mrun = -1e30f, lsum = 0.f;

  const int nkt = CAUSAL ? (qt + 1) : (S >> 6);
  const int nIter = (nkt + 3) >> 2;

  for (int i = 0; i < nIter; ++i) {
    const int kt = ks + 4 * i;
    const bool active = kt < nkt;
    if (active) {
#pragma unroll
      for (int j = 0; j < 4; ++j) {
        int c = j * 128 + ts, row = c >> 3, c16 = c & 7;
        int sw = (c16 * 16) ^ ((row & 7) << 4);
        gload16((const char*)(K + (size_t)(kt * 64 + row) * kstride + hd0) + sw, (char*)kL + c * 16);
      }
#pragma unroll
      for (int j = 0; j < 4; ++j) {
        int c = j * 128 + ts, row = c >> 3, c16 = c & 7;
        int sw = (c16 * 16) ^ ((row & 7) << 4);
        gload16((const char*)(VT + (size_t)(hd0 + row) * S + kt * 64) + sw, (char*)vL + c * 16);
      }
    }
    __syncthreads();
    if (active) {
      f32x16 s0 = {}, s1 = {};
#pragma unroll
      for (int sl = 0; sl < 4; ++sl) {
        int cb = sl * 32 + hi * 16;
        int r0 = lo5, r1 = 32 + lo5;
        bf16x8 kf0 = *(const bf16x8*)((const char*)kL + r0 * 128 + (cb ^ ((r0 & 7) << 4)));
        bf16x8 kf1 = *(const bf16x8*)((const char*)kL + r1 * 128 + (cb ^ ((r1 & 7) << 4)));
        s0 = __builtin_amdgcn_mfma_f32_32x32x16_bf16(kf0, qf[sl], s0, 0, 0, 0);
        s1 = __builtin_amdgcn_mfma_f32_32x32x16_bf16(kf1, qf[sl], s1, 0, 0, 0);
      }

      if (CAUSAL && kt == qt) {
        int qg = q0 + lo5;
#pragma unroll
        for (int r = 0; r < 16; ++r) {
          int kg = kt * 64 + (r & 3) + 8 * (r >> 2) + 4 * hi;
          if (kg > qg) s0[r] = -1e30f;
          if (kg + 32 > qg) s1[r] = -1e30f;
        }
      }

      float pm = s0[0];
#pragma unroll
      for (int r = 1; r < 16; ++r) pm = fmaxf(pm, s0[r]);
#pragma unroll
      for (int r = 0; r < 16; ++r) pm = fmaxf(pm, s1[r]);
      pm = fmaxf(pm, __shfl_xor(pm, 32));

      float mnew = fmaxf(mrun, pm);
      float sc = exp2f(mrun - mnew);
      lsum *= sc;
#pragma unroll
      for (int r = 0; r < 16; ++r) { oa0[r] *= sc; oa1[r] *= sc; }
      mrun = mnew;

      float ps = 0.f;
#pragma unroll
      for (int r = 0; r < 16; ++r) { s0[r] = exp2f(s0[r] - mrun); ps += s0[r]; }
#pragma unroll
      for (int r = 0; r < 16; ++r) { s1[r] = exp2f(s1[r] - mrun); ps += s1[r]; }
      ps += __shfl_xor(ps, 32);
      lsum += ps;

#pragma unroll
      for (int ksl = 0; ksl < 4; ++ksl) {
        const int base = 8 * (ksl & 1);
        float pA0, pA1, pA2, pA3, pB0, pB1, pB2, pB3;
        if (ksl < 2) {
          pA0 = s0[base + 0]; pA1 = s0[base + 1]; pA2 = s0[base + 2]; pA3 = s0[base + 3];
          pB0 = s0[base + 4]; pB1 = s0[base + 5]; pB2 = s0[base + 6]; pB3 = s0[base + 7];
        } else {
          pA0 = s1[base + 0]; pA1 = s1[base + 1]; pA2 = s1[base + 2]; pA3 = s1[base + 3];
          pB0 = s1[base + 4]; pB1 = s1[base + 5]; pB2 = s1[base + 6]; pB3 = s1[base + 7];
        }
        unsigned a01 = pack2(pA0, pA1), a23 = pack2(pA2, pA3);
        unsigned b01 = pack2(pB0, pB1), b23 = pack2(pB2, pB3);
        unsigned xa01 = __shfl_xor(a01, 32), xa23 = __shfl_xor(a23, 32);
        unsigned xb01 = __shfl_xor(b01, 32), xb23 = __shfl_xor(b23, 32);
        union { unsigned u[4]; bf16x8 v; } pf;
        pf.u[0] = hi ? xb01 : a01;
        pf.u[1] = hi ? xb23 : a23;
        pf.u[2] = hi ? b01 : xa01;
        pf.u[3] = hi ? b23 : xa23;
        int cb = ksl * 32 + hi * 16;
        int r0 = lo5, r1 = 32 + lo5;
        bf16x8 vf0 = *(const bf16x8*)((const char*)vL + r0 * 128 + (cb ^ ((r0 & 7) << 4)));
        bf16x8 vf1 = *(const bf16x8*)((const char*)vL + r1 * 128 + (cb ^ ((r1 & 7) << 4)));
        oa0 = __builtin_amdgcn_mfma_f32_32x32x16_bf16(vf0, pf.v, oa0, 0, 0, 0);
        oa1 = __builtin_amdgcn_mfma_f32_32x32x16_bf16(vf1, pf.v, oa1, 0, 0, 0);
      }
    }
    __syncthreads();
  }

  // ---- merge across splits ----
  float* mlBuf = (float*)(smem + 65536);
#define OB_BYTE(g, halfoff) (lo5 * 256 + (((halfoff) + 32 * (g) + 16 * hi) ^ ((lo5 & 15) << 4)))
  if (ks >= 2) {
    char* ob = smem + (qw * 2 + (ks - 2)) * 8192;
#pragma unroll
    for (int g = 0; g < 4; ++g) {
      *(float4*)(ob + OB_BYTE(g, 0)) = make_float4(oa0[4 * g + 0], oa0[4 * g + 1], oa0[4 * g + 2], oa0[4 * g + 3]);
      *(float4*)(ob + OB_BYTE(g, 128)) = make_float4(oa1[4 * g + 0], oa1[4 * g + 1], oa1[4 * g + 2], oa1[4 * g + 3]);
    }
    if (hi == 0) { mlBuf[(w * 32 + lo5) * 2] = mrun; mlBuf[(w * 32 + lo5) * 2 + 1] = lsum; }
  }
  __syncthreads();
  if (ks < 2) {
    int pw = qw * 4 + ks + 2;
    char* ob = smem + (qw * 2 + ks) * 8192;
    float mB = mlBuf[(pw * 32 + lo5) * 2], lB = mlBuf[(pw * 32 + lo5) * 2 + 1];
    float M = fmaxf(mrun, mB);
    float sA = exp2f(mrun - M), sB = exp2f(mB - M);
    lsum = lsum * sA + lB * sB;
    mrun = M;
#pragma unroll
    for (int g = 0; g < 4; ++g) {
      float4 v0 = *(const float4*)(ob + OB_BYTE(g, 0));
      float4 v1 = *(const float4*)(ob + OB_BYTE(g, 128));
      oa0[4 * g + 0] = oa0[4 * g + 0] * sA + v0.x * sB;
      oa0[4 * g + 1] = oa0[4 * g + 1] * sA + v0.y * sB;
      oa0[4 * g + 2] = oa0[4 * g + 2] * sA + v0.z * sB;
      oa0[4 * g + 3] = oa0[4 * g + 3] * sA + v0.w * sB;
      oa1[4 * g + 0] = oa1[4 * g + 0] * sA + v1.x * sB;
      oa1[4 * g + 1] = oa1[4 * g + 1] * sA + v1.y * sB;
      oa1[4 * g + 2] = oa1[4 * g + 2] * sA + v1.z * sB;
      oa1[4 * g + 3] = oa1[4 * g + 3] * sA + v1.w * sB;
    }
  }
  if (ks == 1) {
    char* ob = smem + 32768 + qw * 8192;
#pragma unroll
    for (int g = 0; g < 4; ++g) {
      *(float4*)(ob + OB_BYTE(g, 0)) = make_float4(oa0[4 * g + 0], oa0[4 * g + 1], oa0[4 * g + 2], oa0[4 * g + 3]);
      *(float4*)(ob + OB_BYTE(g, 128)) = make_float4(oa1[4 * g + 0], oa1[4 * g + 1], oa1[4 * g + 2], oa1[4 * g + 3]);
    }
    if (hi == 0) { mlBuf[(w * 32 + lo5) * 2] = mrun; mlBuf[(w * 32 + lo5) * 2 + 1] = lsum; }
  }
  __syncthreads();
  if (ks == 0) {
    int pw = qw * 4 + 1;
    char* ob = smem + 32768 + qw * 8192;
    float mB = mlBuf[(pw * 32 + lo5) * 2], lB = mlBuf[(pw * 32 + lo5) * 2 + 1];
    float M = fmaxf(mrun, mB);
    float sA = exp2f(mrun - M), sB = exp2f(mB - M);
    lsum = lsum * sA + lB * sB;
#pragma unroll
    for (int g = 0; g < 4; ++g) {
      float4 v0 = *(const float4*)(ob + OB_BYTE(g, 0));
      float4 v1 = *(const float4*)(ob + OB_BYTE(g, 128));
      oa0[4 * g + 0] = oa0[4 * g + 0] * sA + v0.x * sB;
      oa0[4 * g + 1] = oa0[4 * g + 1] * sA + v0.y * sB;
      oa0[4 * g + 2] = oa0[4 * g + 2] * sA + v0.z * sB;
      oa0[4 * g + 3] = oa0[4 * g + 3] * sA + v0.w * sB;
      oa1[4 * g + 0] = oa1[4 * g + 0] * sA + v1.x * sB;
      oa1[4 * g + 1] = oa1[4 * g + 1] * sA + v1.y * sB;
      oa1[4 * g + 2] = oa1[4 * g + 2] * sA + v1.z * sB;
      oa1[4 * g + 3] = oa1[4 * g + 3] * sA + v1.w * sB;
    }
    float inv = 1.f / lsum;
    u16* ldsO = (u16*)(smem + 65536 + 2048);
    int qrow = qw * 32 + lo5;
#pragma unroll
    for (int g = 0; g < 4; ++g) {
      unsigned w0 = pack2(oa0[4 * g + 0] * inv, oa0[4 * g + 1] * inv);
      unsigned w1 = pack2(oa0[4 * g + 2] * inv, oa0[4 * g + 3] * inv);
      int dby = (8 * g + 4 * hi) * 2;
      *(uint2*)((char*)ldsO + qrow * 128 + (dby ^ ((qrow & 7) << 4))) = make_uint2(w0, w1);
      unsigned w2 = pack2(oa1[4 * g + 0] * inv, oa1[4 * g + 1] * inv);
      unsigned w3 = pack2(oa1[4 * g + 2] * inv, oa1[4 * g + 3] * inv);
      int dby2 = (32 + 8 * g + 4 * hi) * 2;
      *(uint2*)((char*)ldsO + qrow * 128 + (dby2 ^ ((qrow & 7) << 4))) = make_uint2(w2, w3);
    }
  }
  __syncthreads();
  {
    u16* ldsO = (u16*)(smem + 65536 + 2048);
    int c = t, row = c >> 3, c16 = c & 7;
    uint4 val = *(const uint4*)((const char*)ldsO + row * 128 + ((c16 * 16) ^ ((row & 7) << 4)));
    *(uint4*)(O + (size_t)(qt * 64 + row) * 1024 + hd0 + c16 * 8) = val;
  }
#undef OB_BYTE
}

// ==========================================================================================
extern "C" void kernel_launch(void* const* d_in, const int* in_sizes, int n_in,
                              void* d_out, int out_size, void* d_ws, size_t ws_size,
                              hipStream_t stream) {
  const float* features = (const float*)d_in[0];
  const float* enc      = (const float*)d_in[1];
  const float* g1a = (const float*)d_in[2];  const float* b1a = (const float*)d_in[3];
  const float* g1b = (const float*)d_in[4];  const float* b1b = (const float*)d_in[5];
  const float* g2a = (const float*)d_in[6];  const float* b2a = (const float*)d_in[7];
  const float* g2b = (const float*)d_in[8];  const float* b2b = (const float*)d_in[9];
  const float* sa_qw = (const float*)d_in[10]; const float* sa_qb = (const float*)d_in[11];
  const float* sa_kw = (const float*)d_in[12]; const float* sa_kb = (const float*)d_in[13];
  const float* sa_vw = (const float*)d_in[14]; const float* sa_vb = (const float*)d_in[15];
  const float* sa_pw = (const float*)d_in[16]; const float* sa_pb = (const float*)d_in[17];
  const float* ca_qw = (const float*)d_in[18]; const float* ca_qb = (const float*)d_in[19];
  const float* ca_kw = (const float*)d_in[20]; const float* ca_kb = (const float*)d_in[21];
  const float* ca_vw = (const float*)d_in[22]; const float* ca_vb = (const float*)d_in[23];
  const float* ca_pw = (const float*)d_in[24]; const float* ca_pb = (const float*)d_in[25];
  const float* m1_w1 = (const float*)d_in[26]; const float* m1_b1 = (const float*)d_in[27];
  const float* m1_w2 = (const float*)d_in[28]; const float* m1_b2 = (const float*)d_in[29];
  const float* m2_w1 = (const float*)d_in[30]; const float* m2_b1 = (const float*)d_in[31];
  const float* m2_w2 = (const float*)d_in[32]; const float* m2_b2 = (const float*)d_in[33];

  const int S = 2048, C = 1024, Mh = 4096;
  const size_t CC = (size_t)C * C;
  float* xout = (float*)d_out;

  char* p = (char*)d_ws;
  auto take = [&](size_t bytes) { char* q = p; p += (bytes + 255) & ~(size_t)255; return q; };
  u16* wt_qkv  = (u16*)take(3 * CC * 2);
  u16* wt_sap  = (u16*)take(CC * 2);
  u16* wt_cap  = (u16*)take(CC * 2);
  u16* wt_caq  = (u16*)take(CC * 2);
  u16* wt_ckv  = (u16*)take(2 * CC * 2);
  u16* wt_m1w1 = (u16*)take((size_t)C * Mh * 2);
  u16* wt_m1w2 = (u16*)take((size_t)C * Mh * 2);
  u16* wt_m2w1 = (u16*)take((size_t)C * Mh * 2);
  u16* wt_m2w2 = (u16*)take((size_t)C * Mh * 2);
  float* bias_qkv = (float*)take(3 * C * 4);
  float* bias_ckv = (float*)take(2 * C * 4);
  u16* xn   = (u16*)take((size_t)S * C * 2);
  u16* encb = (u16*)take((size_t)S * C * 2);
  u16* vtbuf = (u16*)take((size_t)C * S * 2);
  u16* abuf  = (u16*)take((size_t)S * C * 2);
  u16* hbuf  = (u16*)take((size_t)S * Mh * 2);
  u16* qkbuf = hbuf;                            // self Q|K packed [S][2048]
  u16* qbuf  = hbuf + (size_t)4 * 1024 * 1024;  // cross Q [S][1024]
  u16* kvbuf = hbuf + (size_t)6 * 1024 * 1024;  // cross K [S][1024]

  dim3 blk(256);
  const float qs2 = 0.125f * 1.4426950408889634f;  // hd^-0.5 * log2(e)
  const int BIG = 1 << 30;

  TransArgs ta;
  ta.src[0] = sa_qw;  ta.dst[0] = wt_qkv;
  ta.src[1] = sa_kw;  ta.dst[1] = wt_qkv + CC;
  ta.src[2] = sa_vw;  ta.dst[2] = wt_qkv + 2 * CC;
  ta.src[3] = sa_pw;  ta.dst[3] = wt_sap;
  ta.src[4] = ca_pw;  ta.dst[4] = wt_cap;
  ta.src[5] = ca_qw;  ta.dst[5] = wt_caq;
  ta.src[6] = ca_kw;  ta.dst[6] = wt_ckv;
  ta.src[7] = ca_vw;  ta.dst[7] = wt_ckv + CC;
  ta.src[8] = m1_w1;  ta.dst[8] = wt_m1w1;   // K=1024, N=4096
  ta.src[9] = m1_w2;  ta.dst[9] = wt_m1w2;   // K=4096, N=1024
  ta.src[10] = m2_w1; ta.dst[10] = wt_m2w1;
  ta.src[11] = m2_w2; ta.dst[11] = wt_m2w2;
  k_transpose_all<<<dim3(8192 + 16384), blk, 0, stream>>>(ta);
  k_cvt<<<dim3(S * C / 1024), blk, 0, stream>>>(enc, encb, S * C / 4);
  k_biaspack<<<20, blk, 0, stream>>>(bias_qkv, bias_ckv, sa_qb, sa_kb, sa_vb, ca_kb, ca_vb);

  // --- block 1: self-attention (causal)
  k_ln<<<S, blk, 0, stream>>>(features, g1a, b1a, xn);
  k_gemm<0, 64><<<dim3(24, 32), blk, 0, stream>>>(xn, wt_qkv, bias_qkv, nullptr, qkbuf, vtbuf,
                                                  S, 3072, C, 2048, qs2, 1024, 2048);
  k_attn3<true><<<dim3(16, 32), dim3(512), 0, stream>>>(qkbuf, qkbuf + 1024, vtbuf, abuf, S, 2048, 2048);
  k_gemm<1, 64><<<dim3(8, 32), blk, 0, stream>>>(abuf, wt_sap, sa_pb, features, xout, nullptr,
                                                 S, C, C, C, 1.f, 0, BIG);
  // --- MLP 1
  k_ln<<<S, blk, 0, stream>>>(xout, g1b, b1b, xn);
  k_gemm<2, 128><<<dim3(32, 16), blk, 0, stream>>>(xn, wt_m1w1, m1_b1, nullptr, hbuf, nullptr,
                                                   S, Mh, C, Mh, 1.f, 0, BIG);
  k_gemm<1, 64><<<dim3(8, 32), blk, 0, stream>>>(hbuf, wt_m1w2, m1_b2, xout, xout, nullptr,
                                                 S, C, Mh, C, 1.f, 0, BIG);
  // --- block 2: cross-attention
  k_ln<<<S, blk, 0, stream>>>(xout, g2a, b2a, xn);
  k_gemm<0, 64><<<dim3(8, 32), blk, 0, stream>>>(xn, wt_caq, ca_qb, nullptr, qbuf, nullptr,
                                                 S, C, C, C, qs2, 1024, BIG);
  k_gemm<0, 128><<<dim3(16, 16), blk, 0, stream>>>(encb, wt_ckv, bias_ckv, nullptr, kvbuf, vtbuf,
                                                   S, 2048, C, 1024, 1.f, 0, 1024);
  k_attn3<false><<<dim3(16, 32), dim3(512), 0, stream>>>(qbuf, kvbuf, vtbuf, abuf, S, 1024, 1024);
  k_gemm<1, 64><<<dim3(8, 32), blk, 0, stream>>>(abuf, wt_cap, ca_pb, xout, xout, nullptr,
                                                 S, C, C, C, 1.f, 0, BIG);
  // --- MLP 2
  k_ln<<<S, blk, 0, stream>>>(xout, g2b, b2b, xn);
  k_gemm<2, 128><<<dim3(32, 16), blk, 0, stream>>>(xn, wt_m2w1, m2_b1, nullptr, hbuf, nullptr,
                                                   S, Mh, C, Mh, 1.f, 0, BIG);
  k_gemm<1, 64><<<dim3(8, 32), blk, 0, stream>>>(hbuf, wt_m2w2, m2_b2, xout, xout, nullptr,
                                                 S, C, Mh, C, 1.f, 0, BIG);
}

// Round 7
// 371.164 us; speedup vs baseline: 1.8820x; 1.1851x over previous
//
#include <hip/hip_runtime.h>
#include <math.h>

typedef unsigned short u16;
typedef __bf16 bf16_t;
typedef bf16_t bf16x8 __attribute__((ext_vector_type(8)));
typedef float f32x4 __attribute__((ext_vector_type(4)));
typedef float f32x16 __attribute__((ext_vector_type(16)));

#define DI __device__ __forceinline__

DI u16 f2bf(float f) {
  union { float f; unsigned u; } c; c.f = f;
  unsigned r = c.u + 0x7FFFu + ((c.u >> 16) & 1u);
  return (u16)(r >> 16);
}

DI unsigned pack2(float lo, float hi_) {
  return (unsigned)f2bf(lo) | ((unsigned)f2bf(hi_) << 16);
}

typedef __attribute__((address_space(1))) void* gas_ptr;
typedef __attribute__((address_space(3))) void* las_ptr;

DI void gload16(const void* g, void* l) {
  __builtin_amdgcn_global_load_lds((gas_ptr)g, (las_ptr)l, 16, 0, 0);
}

// ---------------- fused transpose+convert of all 12 weights ----------------
struct TransArgs { const float* src[12]; u16* dst[12]; };
__global__ __launch_bounds__(256) void k_transpose_all(TransArgs ta) {
  __shared__ float tile[32][33];
  int bx = blockIdx.x;
  int z, local, K, N;
  if (bx < 8192) { z = bx >> 10; local = bx & 1023; K = 1024; N = 1024; }
  else {
    int i = bx - 8192; z = 8 + (i >> 12); local = i & 4095;
    if (z & 1) { K = 4096; N = 1024; } else { K = 1024; N = 4096; }
  }
  const float* w = ta.src[z];
  u16* wt = ta.dst[z];
  int nT = N >> 5;
  int n0 = (local % nT) * 32, k0 = (local / nT) * 32;
  int tx = threadIdx.x & 31, ty = threadIdx.x >> 5;
  for (int r = ty; r < 32; r += 8)
    tile[r][tx] = w[(size_t)(k0 + r) * N + n0 + tx];
  __syncthreads();
  for (int r = ty; r < 32; r += 8)
    wt[(size_t)(n0 + r) * K + k0 + tx] = f2bf(tile[tx][r]);
}

// ---------------- f32 -> bf16 elementwise ----------------
__global__ __launch_bounds__(256) void k_cvt(const float* __restrict__ in, u16* __restrict__ out, int n4) {
  int i = blockIdx.x * 256 + threadIdx.x;
  if (i < n4) {
    float4 v = ((const float4*)in)[i];
    ushort4 o;
    o.x = f2bf(v.x); o.y = f2bf(v.y); o.z = f2bf(v.z); o.w = f2bf(v.w);
    ((ushort4*)out)[i] = o;
  }
}

// ---------------- bias packing ----------------
__global__ __launch_bounds__(256) void k_biaspack(float* __restrict__ bq, float* __restrict__ bc,
                                                  const float* qb, const float* kb, const float* vb,
                                                  const float* ckb, const float* cvb) {
  int i = blockIdx.x * 256 + threadIdx.x;
  if (i < 1024) bq[i] = qb[i];
  else if (i < 2048) bq[i] = kb[i - 1024];
  else if (i < 3072) bq[i] = vb[i - 2048];
  else if (i < 4096) bc[i - 3072] = ckb[i - 3072];
  else if (i < 5120) bc[i - 3072] = cvb[i - 4096];
}

// ---------------- LayerNorm over C=1024, fp32 in -> bf16 out ----------------
__global__ __launch_bounds__(256) void k_ln(const float* __restrict__ x, const float* __restrict__ g,
                                            const float* __restrict__ b, u16* __restrict__ out) {
  int row = blockIdx.x, t = threadIdx.x;
  const float4 v = ((const float4*)(x + (size_t)row * 1024))[t];
  float s = v.x + v.y + v.z + v.w;
  float ss = v.x * v.x + v.y * v.y + v.z * v.z + v.w * v.w;
  for (int o = 32; o; o >>= 1) { s += __shfl_down(s, o); ss += __shfl_down(ss, o); }
  __shared__ float red[10];
  int w = t >> 6;
  if ((t & 63) == 0) { red[w] = s; red[4 + w] = ss; }
  __syncthreads();
  if (t == 0) {
    float S = red[0] + red[1] + red[2] + red[3];
    float SS = red[4] + red[5] + red[6] + red[7];
    float mean = S * (1.f / 1024.f);
    float var = SS * (1.f / 1024.f) - mean * mean;
    red[8] = mean; red[9] = rsqrtf(var + 1e-6f);
  }
  __syncthreads();
  float mean = red[8], rstd = red[9];
  float4 gg = ((const float4*)g)[t], bb = ((const float4*)b)[t];
  ushort4 o4;
  o4.x = f2bf((v.x - mean) * rstd * gg.x + bb.x);
  o4.y = f2bf((v.y - mean) * rstd * gg.y + bb.y);
  o4.z = f2bf((v.z - mean) * rstd * gg.z + bb.z);
  o4.w = f2bf((v.w - mean) * rstd * gg.w + bb.w);
  ((ushort4*)(out + (size_t)row * 1024))[t] = o4;
}

// ---------------- GEMM (wide-N): out[M,N] = A[M,K] @ Bt[N,K]^T + bias, BM=64, BN=128 ----------
// MODE 0: bf16 out (scale cols < scale_end); cols >= vcol0 written TRANSPOSED to vtout.
// MODE 2: bf16 out = gelu(acc + bias).
template <int MODE>
__global__ __launch_bounds__(256) void k_gemm(const u16* __restrict__ A, const u16* __restrict__ Bt,
                                              const float* __restrict__ bias, void* outv, u16* vtout,
                                              int M, int N, int K, int ostride,
                                              float scale, int scale_end, int vcol0) {
  constexpr int BM = 64, NT = 2;
  __shared__ u16 aL[2][BM * 64];
  __shared__ u16 bL[2][128 * 64];
  const int lane = threadIdx.x & 63, w = threadIdx.x >> 6, t = threadIdx.x;
  const int wn = w;
  const int m0 = blockIdx.y * BM, n0 = blockIdx.x * 128;

  f32x4 acc[4][NT];
#pragma unroll
  for (int i = 0; i < 4; ++i)
#pragma unroll
    for (int j = 0; j < NT; ++j) acc[i][j] = (f32x4){0.f, 0.f, 0.f, 0.f};

  auto stage = [&](int buf, int kt) {
    const int k0 = kt << 6;
#pragma unroll
    for (int c = t; c < BM * 8; c += 256) {
      int row = c >> 3, c16 = c & 7;
      int sw = (c16 * 16) ^ ((row & 7) << 4);
      gload16((const char*)(A + (size_t)(m0 + row) * K + k0) + sw, (char*)aL[buf] + c * 16);
    }
#pragma unroll
    for (int c = t; c < 1024; c += 256) {
      int row = c >> 3, c16 = c & 7;
      int sw = (c16 * 16) ^ ((row & 7) << 4);
      gload16((const char*)(Bt + (size_t)(n0 + row) * K + k0) + sw, (char*)bL[buf] + c * 16);
    }
  };

  const int nkt = K >> 6;
  stage(0, 0);
  __syncthreads();
  int cur = 0;
  for (int kt = 0; kt < nkt; ++kt) {
    if (kt + 1 < nkt) stage(cur ^ 1, kt + 1);
#pragma unroll
    for (int kk = 0; kk < 2; ++kk) {
      const int cb = kk * 64 + ((lane >> 4) << 4);
      bf16x8 af[4], bfr[NT];
#pragma unroll
      for (int mi = 0; mi < 4; ++mi) {
        int row = mi * 16 + (lane & 15);
        af[mi] = *(const bf16x8*)((const char*)aL[cur] + row * 128 + (cb ^ ((row & 7) << 4)));
      }
#pragma unroll
      for (int ni = 0; ni < NT; ++ni) {
        int row = wn * 32 + ni * 16 + (lane & 15);
        bfr[ni] = *(const bf16x8*)((const char*)bL[cur] + row * 128 + (cb ^ ((row & 7) << 4)));
      }
#pragma unroll
      for (int mi = 0; mi < 4; ++mi)
#pragma unroll
        for (int ni = 0; ni < NT; ++ni)
          acc[mi][ni] = __builtin_amdgcn_mfma_f32_16x16x32_bf16(af[mi], bfr[ni], acc[mi][ni], 0, 0, 0);
    }
    __syncthreads();
    cur ^= 1;
  }

  const int cBase = n0 + wn * 32 + (lane & 15);
  const int rBase = m0 + ((lane >> 4) << 2);
#pragma unroll
  for (int ni = 0; ni < NT; ++ni) {
    int col = cBase + ni * 16;
    float bv = bias[col];
#pragma unroll
    for (int mi = 0; mi < 4; ++mi) {
      int row = rBase + mi * 16;
      f32x4 a = acc[mi][ni];
      if (MODE == 0) {
        float sc = (col < scale_end) ? scale : 1.f;
        if (col >= vcol0) {
          ushort4 o4;
          o4.x = f2bf((a[0] + bv) * sc); o4.y = f2bf((a[1] + bv) * sc);
          o4.z = f2bf((a[2] + bv) * sc); o4.w = f2bf((a[3] + bv) * sc);
          *(ushort4*)(vtout + (size_t)(col - vcol0) * M + row) = o4;
        } else {
#pragma unroll
          for (int r = 0; r < 4; ++r)
            ((u16*)outv)[(size_t)(row + r) * ostride + col] = f2bf((a[r] + bv) * sc);
        }
      } else {
#pragma unroll
        for (int r = 0; r < 4; ++r) {
          float v = a[r] + bv;
          ((u16*)outv)[(size_t)(row + r) * ostride + col] =
              f2bf(0.5f * v * (1.f + erff(v * 0.70710678118654752f)));
        }
      }
    }
  }
}

// ---------------- GEMM (skinny-N): 2-way in-block split-K, BM=BN=64, 8 waves ----------------
// waves 0-3 compute K[0:K/2), waves 4-7 K[K/2:K); f32 merge via LDS (reuses staging space).
// MODE 0: bf16 out = (acc+bias)*scale.   MODE 1: f32 out = res + acc + bias.
template <int MODE>
__global__ __launch_bounds__(512, 2) void k_gemm_sk(const u16* __restrict__ A, const u16* __restrict__ Bt,
                                                    const float* __restrict__ bias, const float* res,
                                                    void* outv, int M, int N, int K, float scale) {
  __shared__ u16 aL[2][2][64 * 64];   // [half][buf]
  __shared__ u16 bL[2][2][64 * 64];
  const int t = threadIdx.x, lane = t & 63, w = t >> 6;
  const int kh = w >> 2, ws2 = w & 3;
  const int ts = t & 255;
  const int m0 = blockIdx.y * 64, n0 = blockIdx.x * 64;
  const int nktH = (K >> 6) >> 1;
  const int kbase = kh * nktH;

  f32x4 acc[4];
#pragma unroll
  for (int i = 0; i < 4; ++i) acc[i] = (f32x4){0.f, 0.f, 0.f, 0.f};

  auto stage = [&](int buf, int kt) {
    const int k0 = (kbase + kt) << 6;
#pragma unroll
    for (int i = 0; i < 2; ++i) {
      int c = i * 256 + ts;
      int row = c >> 3, c16 = c & 7;
      int sw = (c16 * 16) ^ ((row & 7) << 4);
      gload16((const char*)(A + (size_t)(m0 + row) * K + k0) + sw, (char*)aL[kh][buf] + c * 16);
      gload16((const char*)(Bt + (size_t)(n0 + row) * K + k0) + sw, (char*)bL[kh][buf] + c * 16);
    }
  };

  stage(0, 0);
  __syncthreads();
  int cur = 0;
  for (int kt = 0; kt < nktH; ++kt) {
    if (kt + 1 < nktH) stage(cur ^ 1, kt + 1);
#pragma unroll
    for (int kk = 0; kk < 2; ++kk) {
      const int cb = kk * 64 + ((lane >> 4) << 4);
      bf16x8 af[4], bfr;
#pragma unroll
      for (int mi = 0; mi < 4; ++mi) {
        int row = mi * 16 + (lane & 15);
        af[mi] = *(const bf16x8*)((const char*)aL[kh][cur] + row * 128 + (cb ^ ((row & 7) << 4)));
      }
      {
        int row = ws2 * 16 + (lane & 15);
        bfr = *(const bf16x8*)((const char*)bL[kh][cur] + row * 128 + (cb ^ ((row & 7) << 4)));
      }
#pragma unroll
      for (int mi = 0; mi < 4; ++mi)
        acc[mi] = __builtin_amdgcn_mfma_f32_16x16x32_bf16(af[mi], bfr, acc[mi], 0, 0, 0);
    }
    __syncthreads();
    cur ^= 1;
  }

  // merge: kh=1 -> LDS (reuse staging), kh=0 adds + epilogue
  float* mergeF = (float*)aL;   // [4][64][17] floats = 17.4 KB < 32 KB
  const int r0l = (lane >> 4) << 2, col16 = lane & 15;
  if (kh == 1) {
#pragma unroll
    for (int mi = 0; mi < 4; ++mi)
#pragma unroll
      for (int r = 0; r < 4; ++r)
        mergeF[(ws2 * 64 + mi * 16 + r0l + r) * 17 + col16] = acc[mi][r];
  }
  __syncthreads();
  if (kh == 0) {
    int col = n0 + ws2 * 16 + col16;
    float bv = bias[col];
#pragma unroll
    for (int mi = 0; mi < 4; ++mi) {
      int row = m0 + mi * 16 + r0l;
#pragma unroll
      for (int r = 0; r < 4; ++r) {
        float v = acc[mi][r] + mergeF[(ws2 * 64 + mi * 16 + r0l + r) * 17 + col16] + bv;
        size_t idx = (size_t)(row + r) * N + col;
        if (MODE == 0) ((u16*)outv)[idx] = f2bf(v * scale);
        else ((float*)outv)[idx] = res[idx] + v;
      }
    }
  }
}

// ---------------- flash attention, split-KV x4 in-block, swapped 32x32 ----------------
template <bool CAUSAL>
__global__ __launch_bounds__(512, 2) void k_attn3(const u16* __restrict__ Q, const u16* __restrict__ K,
                                                  const u16* __restrict__ VT, u16* __restrict__ O,
                                                  int S, int qstride, int kstride) {
  __shared__ __align__(16) char smem[64 * 1024 + 2048 + 8192];
  const int t = threadIdx.x, lane = t & 63, w = t >> 6;   // w 0..7
  const int ks = w & 3, qw = w >> 2;                      // split 0..3, q-wave 0..1
  const int lo5 = lane & 31, hi = lane >> 5;
  const int h = blockIdx.x;
  const int bq = blockIdx.y;
  const int qt = (bq & 1) ? (31 - (bq >> 1)) : (bq >> 1); // light/heavy interleave (bijective)
  const int hd0 = h * 64;
  const int q0 = qt * 64 + qw * 32;
  const int ts = qw * 64 + lane;                          // 0..127 within split

  u16* kL = (u16*)(smem + ks * 16384);
  u16* vL = (u16*)(smem + ks * 16384 + 8192);

  bf16x8 qf[4];
#pragma unroll
  for (int sl = 0; sl < 4; ++sl)
    qf[sl] = *(const bf16x8*)(Q + (size_t)(q0 + lo5) * qstride + hd0 + sl * 16 + hi * 8);

  f32x16 oa0 = {}, oa1 = {};
  float mrun = -1e30f, lsum = 0.f;

  const int nkt = CAUSAL ? (qt + 1) : (S >> 6);
  const int nIter = (nkt + 3) >> 2;

  for (int i = 0; i < nIter; ++i) {
    const int kt = ks + 4 * i;
    const bool active = kt < nkt;
    if (active) {
#pragma unroll
      for (int j = 0; j < 4; ++j) {
        int c = j * 128 + ts, row = c >> 3, c16 = c & 7;
        int sw = (c16 * 16) ^ ((row & 7) << 4);
        gload16((const char*)(K + (size_t)(kt * 64 + row) * kstride + hd0) + sw, (char*)kL + c * 16);
      }
#pragma unroll
      for (int j = 0; j < 4; ++j) {
        int c = j * 128 + ts, row = c >> 3, c16 = c & 7;
        int sw = (c16 * 16) ^ ((row & 7) << 4);
        gload16((const char*)(VT + (size_t)(hd0 + row) * S + kt * 64) + sw, (char*)vL + c * 16);
      }
    }
    __syncthreads();
    if (active) {
      f32x16 s0 = {}, s1 = {};
#pragma unroll
      for (int sl = 0; sl < 4; ++sl) {
        int cb = sl * 32 + hi * 16;
        int r0 = lo5, r1 = 32 + lo5;
        bf16x8 kf0 = *(const bf16x8*)((const char*)kL + r0 * 128 + (cb ^ ((r0 & 7) << 4)));
        bf16x8 kf1 = *(const bf16x8*)((const char*)kL + r1 * 128 + (cb ^ ((r1 & 7) << 4)));
        s0 = __builtin_amdgcn_mfma_f32_32x32x16_bf16(kf0, qf[sl], s0, 0, 0, 0);
        s1 = __builtin_amdgcn_mfma_f32_32x32x16_bf16(kf1, qf[sl], s1, 0, 0, 0);
      }

      if (CAUSAL && kt == qt) {
        int qg = q0 + lo5;
#pragma unroll
        for (int r = 0; r < 16; ++r) {
          int kg = kt * 64 + (r & 3) + 8 * (r >> 2) + 4 * hi;
          if (kg > qg) s0[r] = -1e30f;
          if (kg + 32 > qg) s1[r] = -1e30f;
        }
      }

      float pm = s0[0];
#pragma unroll
      for (int r = 1; r < 16; ++r) pm = fmaxf(pm, s0[r]);
#pragma unroll
      for (int r = 0; r < 16; ++r) pm = fmaxf(pm, s1[r]);
      pm = fmaxf(pm, __shfl_xor(pm, 32));

      float mnew = fmaxf(mrun, pm);
      float sc = exp2f(mrun - mnew);
      lsum *= sc;
#pragma unroll
      for (int r = 0; r < 16; ++r) { oa0[r] *= sc; oa1[r] *= sc; }
      mrun = mnew;

      float ps = 0.f;
#pragma unroll
      for (int r = 0; r < 16; ++r) { s0[r] = exp2f(s0[r] - mrun); ps += s0[r]; }
#pragma unroll
      for (int r = 0; r < 16; ++r) { s1[r] = exp2f(s1[r] - mrun); ps += s1[r]; }
      ps += __shfl_xor(ps, 32);
      lsum += ps;

#pragma unroll
      for (int ksl = 0; ksl < 4; ++ksl) {
        const int base = 8 * (ksl & 1);
        float pA0, pA1, pA2, pA3, pB0, pB1, pB2, pB3;
        if (ksl < 2) {
          pA0 = s0[base + 0]; pA1 = s0[base + 1]; pA2 = s0[base + 2]; pA3 = s0[base + 3];
          pB0 = s0[base + 4]; pB1 = s0[base + 5]; pB2 = s0[base + 6]; pB3 = s0[base + 7];
        } else {
          pA0 = s1[base + 0]; pA1 = s1[base + 1]; pA2 = s1[base + 2]; pA3 = s1[base + 3];
          pB0 = s1[base + 4]; pB1 = s1[base + 5]; pB2 = s1[base + 6]; pB3 = s1[base + 7];
        }
        unsigned a01 = pack2(pA0, pA1), a23 = pack2(pA2, pA3);
        unsigned b01 = pack2(pB0, pB1), b23 = pack2(pB2, pB3);
        unsigned xa01 = __shfl_xor(a01, 32), xa23 = __shfl_xor(a23, 32);
        unsigned xb01 = __shfl_xor(b01, 32), xb23 = __shfl_xor(b23, 32);
        union { unsigned u[4]; bf16x8 v; } pf;
        pf.u[0] = hi ? xb01 : a01;
        pf.u[1] = hi ? xb23 : a23;
        pf.u[2] = hi ? b01 : xa01;
        pf.u[3] = hi ? b23 : xa23;
        int cb = ksl * 32 + hi * 16;
        int r0 = lo5, r1 = 32 + lo5;
        bf16x8 vf0 = *(const bf16x8*)((const char*)vL + r0 * 128 + (cb ^ ((r0 & 7) << 4)));
        bf16x8 vf1 = *(const bf16x8*)((const char*)vL + r1 * 128 + (cb ^ ((r1 & 7) << 4)));
        oa0 = __builtin_amdgcn_mfma_f32_32x32x16_bf16(vf0, pf.v, oa0, 0, 0, 0);
        oa1 = __builtin_amdgcn_mfma_f32_32x32x16_bf16(vf1, pf.v, oa1, 0, 0, 0);
      }
    }
    __syncthreads();
  }

  // ---- merge across splits ----
  float* mlBuf = (float*)(smem + 65536);
#define OB_BYTE(g, halfoff) (lo5 * 256 + (((halfoff) + 32 * (g) + 16 * hi) ^ ((lo5 & 15) << 4)))
  if (ks >= 2) {
    char* ob = smem + (qw * 2 + (ks - 2)) * 8192;
#pragma unroll
    for (int g = 0; g < 4; ++g) {
      *(float4*)(ob + OB_BYTE(g, 0)) = make_float4(oa0[4 * g + 0], oa0[4 * g + 1], oa0[4 * g + 2], oa0[4 * g + 3]);
      *(float4*)(ob + OB_BYTE(g, 128)) = make_float4(oa1[4 * g + 0], oa1[4 * g + 1], oa1[4 * g + 2], oa1[4 * g + 3]);
    }
    if (hi == 0) { mlBuf[(w * 32 + lo5) * 2] = mrun; mlBuf[(w * 32 + lo5) * 2 + 1] = lsum; }
  }
  __syncthreads();
  if (ks < 2) {
    int pw = qw * 4 + ks + 2;
    char* ob = smem + (qw * 2 + ks) * 8192;
    float mB = mlBuf[(pw * 32 + lo5) * 2], lB = mlBuf[(pw * 32 + lo5) * 2 + 1];
    float M = fmaxf(mrun, mB);
    float sA = exp2f(mrun - M), sB = exp2f(mB - M);
    lsum = lsum * sA + lB * sB;
    mrun = M;
#pragma unroll
    for (int g = 0; g < 4; ++g) {
      float4 v0 = *(const float4*)(ob + OB_BYTE(g, 0));
      float4 v1 = *(const float4*)(ob + OB_BYTE(g, 128));
      oa0[4 * g + 0] = oa0[4 * g + 0] * sA + v0.x * sB;
      oa0[4 * g + 1] = oa0[4 * g + 1] * sA + v0.y * sB;
      oa0[4 * g + 2] = oa0[4 * g + 2] * sA + v0.z * sB;
      oa0[4 * g + 3] = oa0[4 * g + 3] * sA + v0.w * sB;
      oa1[4 * g + 0] = oa1[4 * g + 0] * sA + v1.x * sB;
      oa1[4 * g + 1] = oa1[4 * g + 1] * sA + v1.y * sB;
      oa1[4 * g + 2] = oa1[4 * g + 2] * sA + v1.z * sB;
      oa1[4 * g + 3] = oa1[4 * g + 3] * sA + v1.w * sB;
    }
  }
  if (ks == 1) {
    char* ob = smem + 32768 + qw * 8192;
#pragma unroll
    for (int g = 0; g < 4; ++g) {
      *(float4*)(ob + OB_BYTE(g, 0)) = make_float4(oa0[4 * g + 0], oa0[4 * g + 1], oa0[4 * g + 2], oa0[4 * g + 3]);
      *(float4*)(ob + OB_BYTE(g, 128)) = make_float4(oa1[4 * g + 0], oa1[4 * g + 1], oa1[4 * g + 2], oa1[4 * g + 3]);
    }
    if (hi == 0) { mlBuf[(w * 32 + lo5) * 2] = mrun; mlBuf[(w * 32 + lo5) * 2 + 1] = lsum; }
  }
  __syncthreads();
  if (ks == 0) {
    int pw = qw * 4 + 1;
    char* ob = smem + 32768 + qw * 8192;
    float mB = mlBuf[(pw * 32 + lo5) * 2], lB = mlBuf[(pw * 32 + lo5) * 2 + 1];
    float M = fmaxf(mrun, mB);
    float sA = exp2f(mrun - M), sB = exp2f(mB - M);
    lsum = lsum * sA + lB * sB;
#pragma unroll
    for (int g = 0; g < 4; ++g) {
      float4 v0 = *(const float4*)(ob + OB_BYTE(g, 0));
      float4 v1 = *(const float4*)(ob + OB_BYTE(g, 128));
      oa0[4 * g + 0] = oa0[4 * g + 0] * sA + v0.x * sB;
      oa0[4 * g + 1] = oa0[4 * g + 1] * sA + v0.y * sB;
      oa0[4 * g + 2] = oa0[4 * g + 2] * sA + v0.z * sB;
      oa0[4 * g + 3] = oa0[4 * g + 3] * sA + v0.w * sB;
      oa1[4 * g + 0] = oa1[4 * g + 0] * sA + v1.x * sB;
      oa1[4 * g + 1] = oa1[4 * g + 1] * sA + v1.y * sB;
      oa1[4 * g + 2] = oa1[4 * g + 2] * sA + v1.z * sB;
      oa1[4 * g + 3] = oa1[4 * g + 3] * sA + v1.w * sB;
    }
    float inv = 1.f / lsum;
    u16* ldsO = (u16*)(smem + 65536 + 2048);
    int qrow = qw * 32 + lo5;
#pragma unroll
    for (int g = 0; g < 4; ++g) {
      unsigned w0 = pack2(oa0[4 * g + 0] * inv, oa0[4 * g + 1] * inv);
      unsigned w1 = pack2(oa0[4 * g + 2] * inv, oa0[4 * g + 3] * inv);
      int dby = (8 * g + 4 * hi) * 2;
      *(uint2*)((char*)ldsO + qrow * 128 + (dby ^ ((qrow & 7) << 4))) = make_uint2(w0, w1);
      unsigned w2 = pack2(oa1[4 * g + 0] * inv, oa1[4 * g + 1] * inv);
      unsigned w3 = pack2(oa1[4 * g + 2] * inv, oa1[4 * g + 3] * inv);
      int dby2 = (32 + 8 * g + 4 * hi) * 2;
      *(uint2*)((char*)ldsO + qrow * 128 + (dby2 ^ ((qrow & 7) << 4))) = make_uint2(w2, w3);
    }
  }
  __syncthreads();
  {
    u16* ldsO = (u16*)(smem + 65536 + 2048);
    int c = t, row = c >> 3, c16 = c & 7;
    uint4 val = *(const uint4*)((const char*)ldsO + row * 128 + ((c16 * 16) ^ ((row & 7) << 4)));
    *(uint4*)(O + (size_t)(qt * 64 + row) * 1024 + hd0 + c16 * 8) = val;
  }
#undef OB_BYTE
}

// ==========================================================================================
extern "C" void kernel_launch(void* const* d_in, const int* in_sizes, int n_in,
                              void* d_out, int out_size, void* d_ws, size_t ws_size,
                              hipStream_t stream) {
  const float* features = (const float*)d_in[0];
  const float* enc      = (const float*)d_in[1];
  const float* g1a = (const float*)d_in[2];  const float* b1a = (const float*)d_in[3];
  const float* g1b = (const float*)d_in[4];  const float* b1b = (const float*)d_in[5];
  const float* g2a = (const float*)d_in[6];  const float* b2a = (const float*)d_in[7];
  const float* g2b = (const float*)d_in[8];  const float* b2b = (const float*)d_in[9];
  const float* sa_qw = (const float*)d_in[10]; const float* sa_qb = (const float*)d_in[11];
  const float* sa_kw = (const float*)d_in[12]; const float* sa_kb = (const float*)d_in[13];
  const float* sa_vw = (const float*)d_in[14]; const float* sa_vb = (const float*)d_in[15];
  const float* sa_pw = (const float*)d_in[16]; const float* sa_pb = (const float*)d_in[17];
  const float* ca_qw = (const float*)d_in[18]; const float* ca_qb = (const float*)d_in[19];
  const float* ca_kw = (const float*)d_in[20]; const float* ca_kb = (const float*)d_in[21];
  const float* ca_vw = (const float*)d_in[22]; const float* ca_vb = (const float*)d_in[23];
  const float* ca_pw = (const float*)d_in[24]; const float* ca_pb = (const float*)d_in[25];
  const float* m1_w1 = (const float*)d_in[26]; const float* m1_b1 = (const float*)d_in[27];
  const float* m1_w2 = (const float*)d_in[28]; const float* m1_b2 = (const float*)d_in[29];
  const float* m2_w1 = (const float*)d_in[30]; const float* m2_b1 = (const float*)d_in[31];
  const float* m2_w2 = (const float*)d_in[32]; const float* m2_b2 = (const float*)d_in[33];

  const int S = 2048, C = 1024, Mh = 4096;
  const size_t CC = (size_t)C * C;
  float* xout = (float*)d_out;

  char* p = (char*)d_ws;
  auto take = [&](size_t bytes) { char* q = p; p += (bytes + 255) & ~(size_t)255; return q; };
  u16* wt_qkv  = (u16*)take(3 * CC * 2);
  u16* wt_sap  = (u16*)take(CC * 2);
  u16* wt_cap  = (u16*)take(CC * 2);
  u16* wt_caq  = (u16*)take(CC * 2);
  u16* wt_ckv  = (u16*)take(2 * CC * 2);
  u16* wt_m1w1 = (u16*)take((size_t)C * Mh * 2);
  u16* wt_m1w2 = (u16*)take((size_t)C * Mh * 2);
  u16* wt_m2w1 = (u16*)take((size_t)C * Mh * 2);
  u16* wt_m2w2 = (u16*)take((size_t)C * Mh * 2);
  float* bias_qkv = (float*)take(3 * C * 4);
  float* bias_ckv = (float*)take(2 * C * 4);
  u16* xn   = (u16*)take((size_t)S * C * 2);
  u16* encb = (u16*)take((size_t)S * C * 2);
  u16* vtbuf = (u16*)take((size_t)C * S * 2);
  u16* abuf  = (u16*)take((size_t)S * C * 2);
  u16* hbuf  = (u16*)take((size_t)S * Mh * 2);
  u16* qkbuf = hbuf;                            // self Q|K packed [S][2048]
  u16* qbuf  = hbuf + (size_t)4 * 1024 * 1024;  // cross Q [S][1024]
  u16* kvbuf = hbuf + (size_t)6 * 1024 * 1024;  // cross K [S][1024]

  dim3 blk(256);
  const float qs2 = 0.125f * 1.4426950408889634f;  // hd^-0.5 * log2(e)
  const int BIG = 1 << 30;

  TransArgs ta;
  ta.src[0] = sa_qw;  ta.dst[0] = wt_qkv;
  ta.src[1] = sa_kw;  ta.dst[1] = wt_qkv + CC;
  ta.src[2] = sa_vw;  ta.dst[2] = wt_qkv + 2 * CC;
  ta.src[3] = sa_pw;  ta.dst[3] = wt_sap;
  ta.src[4] = ca_pw;  ta.dst[4] = wt_cap;
  ta.src[5] = ca_qw;  ta.dst[5] = wt_caq;
  ta.src[6] = ca_kw;  ta.dst[6] = wt_ckv;
  ta.src[7] = ca_vw;  ta.dst[7] = wt_ckv + CC;
  ta.src[8] = m1_w1;  ta.dst[8] = wt_m1w1;
  ta.src[9] = m1_w2;  ta.dst[9] = wt_m1w2;
  ta.src[10] = m2_w1; ta.dst[10] = wt_m2w1;
  ta.src[11] = m2_w2; ta.dst[11] = wt_m2w2;
  k_transpose_all<<<dim3(8192 + 16384), blk, 0, stream>>>(ta);
  k_cvt<<<dim3(S * C / 1024), blk, 0, stream>>>(enc, encb, S * C / 4);
  k_biaspack<<<20, blk, 0, stream>>>(bias_qkv, bias_ckv, sa_qb, sa_kb, sa_vb, ca_kb, ca_vb);

  // --- block 1: self-attention (causal)
  k_ln<<<S, blk, 0, stream>>>(features, g1a, b1a, xn);
  k_gemm<0><<<dim3(24, 32), blk, 0, stream>>>(xn, wt_qkv, bias_qkv, qkbuf, vtbuf,
                                              S, 3072, C, 2048, qs2, 1024, 2048);
  k_attn3<true><<<dim3(16, 32), dim3(512), 0, stream>>>(qkbuf, qkbuf + 1024, vtbuf, abuf, S, 2048, 2048);
  k_gemm_sk<1><<<dim3(16, 32), dim3(512), 0, stream>>>(abuf, wt_sap, sa_pb, features, xout, S, C, C, 1.f);
  // --- MLP 1
  k_ln<<<S, blk, 0, stream>>>(xout, g1b, b1b, xn);
  k_gemm<2><<<dim3(32, 32), blk, 0, stream>>>(xn, wt_m1w1, m1_b1, hbuf, nullptr,
                                              S, Mh, C, Mh, 1.f, 0, BIG);
  k_gemm_sk<1><<<dim3(16, 32), dim3(512), 0, stream>>>(hbuf, wt_m1w2, m1_b2, xout, xout, S, C, Mh, 1.f);
  // --- block 2: cross-attention
  k_ln<<<S, blk, 0, stream>>>(xout, g2a, b2a, xn);
  k_gemm_sk<0><<<dim3(16, 32), dim3(512), 0, stream>>>(xn, wt_caq, ca_qb, nullptr, qbuf, S, C, C, qs2);
  k_gemm<0><<<dim3(16, 32), blk, 0, stream>>>(encb, wt_ckv, bias_ckv, kvbuf, vtbuf,
                                              S, 2048, C, 1024, 1.f, 0, 1024);
  k_attn3<false><<<dim3(16, 32), dim3(512), 0, stream>>>(qbuf, kvbuf, vtbuf, abuf, S, 1024, 1024);
  k_gemm_sk<1><<<dim3(16, 32), dim3(512), 0, stream>>>(abuf, wt_cap, ca_pb, xout, xout, S, C, C, 1.f);
  // --- MLP 2
  k_ln<<<S, blk, 0, stream>>>(xout, g2b, b2b, xn);
  k_gemm<2><<<dim3(32, 32), blk, 0, stream>>>(xn, wt_m2w1, m2_b1, hbuf, nullptr,
                                              S, Mh, C, Mh, 1.f, 0, BIG);
  k_gemm_sk<1><<<dim3(16, 32), dim3(512), 0, stream>>>(hbuf, wt_m2w2, m2_b2, xout, xout, S, C, Mh, 1.f);
}

// Round 8
// 360.441 us; speedup vs baseline: 1.9380x; 1.0297x over previous
//
#include <hip/hip_runtime.h>
#include <math.h>

typedef unsigned short u16;
typedef __bf16 bf16_t;
typedef bf16_t bf16x8 __attribute__((ext_vector_type(8)));
typedef float f32x4 __attribute__((ext_vector_type(4)));
typedef float f32x16 __attribute__((ext_vector_type(16)));

#define DI __device__ __forceinline__

DI u16 f2bf(float f) {
  union { float f; unsigned u; } c; c.f = f;
  unsigned r = c.u + 0x7FFFu + ((c.u >> 16) & 1u);
  return (u16)(r >> 16);
}

DI unsigned pack2(float lo, float hi_) {
  return (unsigned)f2bf(lo) | ((unsigned)f2bf(hi_) << 16);
}

DI unsigned cvt_pk(float lo, float hi_) {  // dst[15:0]=bf16(lo), dst[31:16]=bf16(hi_)
  unsigned d;
  asm("v_cvt_pk_bf16_f32 %0, %1, %2" : "=v"(d) : "v"(lo), "v"(hi_));
  return d;
}

typedef __attribute__((address_space(1))) void* gas_ptr;
typedef __attribute__((address_space(3))) void* las_ptr;

DI void gload16(const void* g, void* l) {
  __builtin_amdgcn_global_load_lds((gas_ptr)g, (las_ptr)l, 16, 0, 0);
}

// ---------------- fused transpose+convert of all 12 weights ----------------
struct TransArgs { const float* src[12]; u16* dst[12]; };
__global__ __launch_bounds__(256) void k_transpose_all(TransArgs ta) {
  __shared__ float tile[32][33];
  int bx = blockIdx.x;
  int z, local, K, N;
  if (bx < 8192) { z = bx >> 10; local = bx & 1023; K = 1024; N = 1024; }
  else {
    int i = bx - 8192; z = 8 + (i >> 12); local = i & 4095;
    if (z & 1) { K = 4096; N = 1024; } else { K = 1024; N = 4096; }
  }
  const float* w = ta.src[z];
  u16* wt = ta.dst[z];
  int nT = N >> 5;
  int n0 = (local % nT) * 32, k0 = (local / nT) * 32;
  int tx = threadIdx.x & 31, ty = threadIdx.x >> 5;
  for (int r = ty; r < 32; r += 8)
    tile[r][tx] = w[(size_t)(k0 + r) * N + n0 + tx];
  __syncthreads();
  for (int r = ty; r < 32; r += 8)
    wt[(size_t)(n0 + r) * K + k0 + tx] = f2bf(tile[tx][r]);
}

// ---------------- f32 -> bf16 elementwise ----------------
__global__ __launch_bounds__(256) void k_cvt(const float* __restrict__ in, u16* __restrict__ out, int n4) {
  int i = blockIdx.x * 256 + threadIdx.x;
  if (i < n4) {
    float4 v = ((const float4*)in)[i];
    ushort4 o;
    o.x = f2bf(v.x); o.y = f2bf(v.y); o.z = f2bf(v.z); o.w = f2bf(v.w);
    ((ushort4*)out)[i] = o;
  }
}

// ---------------- bias packing ----------------
__global__ __launch_bounds__(256) void k_biaspack(float* __restrict__ bq, float* __restrict__ bc,
                                                  const float* qb, const float* kb, const float* vb,
                                                  const float* ckb, const float* cvb) {
  int i = blockIdx.x * 256 + threadIdx.x;
  if (i < 1024) bq[i] = qb[i];
  else if (i < 2048) bq[i] = kb[i - 1024];
  else if (i < 3072) bq[i] = vb[i - 2048];
  else if (i < 4096) bc[i - 3072] = ckb[i - 3072];
  else if (i < 5120) bc[i - 3072] = cvb[i - 4096];
}

// ---------------- LayerNorm over C=1024, fp32 in -> bf16 out ----------------
__global__ __launch_bounds__(256) void k_ln(const float* __restrict__ x, const float* __restrict__ g,
                                            const float* __restrict__ b, u16* __restrict__ out) {
  int row = blockIdx.x, t = threadIdx.x;
  const float4 v = ((const float4*)(x + (size_t)row * 1024))[t];
  float s = v.x + v.y + v.z + v.w;
  float ss = v.x * v.x + v.y * v.y + v.z * v.z + v.w * v.w;
  for (int o = 32; o; o >>= 1) { s += __shfl_down(s, o); ss += __shfl_down(ss, o); }
  __shared__ float red[10];
  int w = t >> 6;
  if ((t & 63) == 0) { red[w] = s; red[4 + w] = ss; }
  __syncthreads();
  if (t == 0) {
    float S = red[0] + red[1] + red[2] + red[3];
    float SS = red[4] + red[5] + red[6] + red[7];
    float mean = S * (1.f / 1024.f);
    float var = SS * (1.f / 1024.f) - mean * mean;
    red[8] = mean; red[9] = rsqrtf(var + 1e-6f);
  }
  __syncthreads();
  float mean = red[8], rstd = red[9];
  float4 gg = ((const float4*)g)[t], bb = ((const float4*)b)[t];
  ushort4 o4;
  o4.x = f2bf((v.x - mean) * rstd * gg.x + bb.x);
  o4.y = f2bf((v.y - mean) * rstd * gg.y + bb.y);
  o4.z = f2bf((v.z - mean) * rstd * gg.z + bb.z);
  o4.w = f2bf((v.w - mean) * rstd * gg.w + bb.w);
  ((ushort4*)(out + (size_t)row * 1024))[t] = o4;
}

// ---------------- GEMM (wide-N): BM=64, BN=128, double-buffered ----------------
template <int MODE>
__global__ __launch_bounds__(256) void k_gemm(const u16* __restrict__ A, const u16* __restrict__ Bt,
                                              const float* __restrict__ bias, void* outv, u16* vtout,
                                              int M, int N, int K, int ostride,
                                              float scale, int scale_end, int vcol0) {
  constexpr int BM = 64, NT = 2;
  __shared__ u16 aL[2][BM * 64];
  __shared__ u16 bL[2][128 * 64];
  const int lane = threadIdx.x & 63, w = threadIdx.x >> 6, t = threadIdx.x;
  const int wn = w;
  const int m0 = blockIdx.y * BM, n0 = blockIdx.x * 128;

  f32x4 acc[4][NT];
#pragma unroll
  for (int i = 0; i < 4; ++i)
#pragma unroll
    for (int j = 0; j < NT; ++j) acc[i][j] = (f32x4){0.f, 0.f, 0.f, 0.f};

  auto stage = [&](int buf, int kt) {
    const int k0 = kt << 6;
#pragma unroll
    for (int c = t; c < BM * 8; c += 256) {
      int row = c >> 3, c16 = c & 7;
      int sw = (c16 * 16) ^ ((row & 7) << 4);
      gload16((const char*)(A + (size_t)(m0 + row) * K + k0) + sw, (char*)aL[buf] + c * 16);
    }
#pragma unroll
    for (int c = t; c < 1024; c += 256) {
      int row = c >> 3, c16 = c & 7;
      int sw = (c16 * 16) ^ ((row & 7) << 4);
      gload16((const char*)(Bt + (size_t)(n0 + row) * K + k0) + sw, (char*)bL[buf] + c * 16);
    }
  };

  const int nkt = K >> 6;
  stage(0, 0);
  __syncthreads();
  int cur = 0;
  for (int kt = 0; kt < nkt; ++kt) {
    if (kt + 1 < nkt) stage(cur ^ 1, kt + 1);
#pragma unroll
    for (int kk = 0; kk < 2; ++kk) {
      const int cb = kk * 64 + ((lane >> 4) << 4);
      bf16x8 af[4], bfr[NT];
#pragma unroll
      for (int mi = 0; mi < 4; ++mi) {
        int row = mi * 16 + (lane & 15);
        af[mi] = *(const bf16x8*)((const char*)aL[cur] + row * 128 + (cb ^ ((row & 7) << 4)));
      }
#pragma unroll
      for (int ni = 0; ni < NT; ++ni) {
        int row = wn * 32 + ni * 16 + (lane & 15);
        bfr[ni] = *(const bf16x8*)((const char*)bL[cur] + row * 128 + (cb ^ ((row & 7) << 4)));
      }
#pragma unroll
      for (int mi = 0; mi < 4; ++mi)
#pragma unroll
        for (int ni = 0; ni < NT; ++ni)
          acc[mi][ni] = __builtin_amdgcn_mfma_f32_16x16x32_bf16(af[mi], bfr[ni], acc[mi][ni], 0, 0, 0);
    }
    __syncthreads();
    cur ^= 1;
  }

  const int cBase = n0 + wn * 32 + (lane & 15);
  const int rBase = m0 + ((lane >> 4) << 2);
#pragma unroll
  for (int ni = 0; ni < NT; ++ni) {
    int col = cBase + ni * 16;
    float bv = bias[col];
#pragma unroll
    for (int mi = 0; mi < 4; ++mi) {
      int row = rBase + mi * 16;
      f32x4 a = acc[mi][ni];
      if (MODE == 0) {
        float sc = (col < scale_end) ? scale : 1.f;
        if (col >= vcol0) {
          ushort4 o4;
          o4.x = f2bf((a[0] + bv) * sc); o4.y = f2bf((a[1] + bv) * sc);
          o4.z = f2bf((a[2] + bv) * sc); o4.w = f2bf((a[3] + bv) * sc);
          *(ushort4*)(vtout + (size_t)(col - vcol0) * M + row) = o4;
        } else {
#pragma unroll
          for (int r = 0; r < 4; ++r)
            ((u16*)outv)[(size_t)(row + r) * ostride + col] = f2bf((a[r] + bv) * sc);
        }
      } else {
#pragma unroll
        for (int r = 0; r < 4; ++r) {
          float v = a[r] + bv;
          ((u16*)outv)[(size_t)(row + r) * ostride + col] =
              f2bf(0.5f * v * (1.f + erff(v * 0.70710678118654752f)));
        }
      }
    }
  }
}

// ---------------- GEMM (skinny-N): 2-way in-block split-K, BM=BN=64, 8 waves ----------------
template <int MODE>
__global__ __launch_bounds__(512, 2) void k_gemm_sk(const u16* __restrict__ A, const u16* __restrict__ Bt,
                                                    const float* __restrict__ bias, const float* res,
                                                    void* outv, int M, int N, int K, float scale) {
  __shared__ u16 aL[2][2][64 * 64];   // [half][buf]
  __shared__ u16 bL[2][2][64 * 64];
  const int t = threadIdx.x, lane = t & 63, w = t >> 6;
  const int kh = w >> 2, ws2 = w & 3;
  const int ts = t & 255;
  const int m0 = blockIdx.y * 64, n0 = blockIdx.x * 64;
  const int nktH = (K >> 6) >> 1;
  const int kbase = kh * nktH;

  f32x4 acc[4];
#pragma unroll
  for (int i = 0; i < 4; ++i) acc[i] = (f32x4){0.f, 0.f, 0.f, 0.f};

  auto stage = [&](int buf, int kt) {
    const int k0 = (kbase + kt) << 6;
#pragma unroll
    for (int i = 0; i < 2; ++i) {
      int c = i * 256 + ts;
      int row = c >> 3, c16 = c & 7;
      int sw = (c16 * 16) ^ ((row & 7) << 4);
      gload16((const char*)(A + (size_t)(m0 + row) * K + k0) + sw, (char*)aL[kh][buf] + c * 16);
      gload16((const char*)(Bt + (size_t)(n0 + row) * K + k0) + sw, (char*)bL[kh][buf] + c * 16);
    }
  };

  stage(0, 0);
  __syncthreads();
  int cur = 0;
  for (int kt = 0; kt < nktH; ++kt) {
    if (kt + 1 < nktH) stage(cur ^ 1, kt + 1);
#pragma unroll
    for (int kk = 0; kk < 2; ++kk) {
      const int cb = kk * 64 + ((lane >> 4) << 4);
      bf16x8 af[4], bfr;
#pragma unroll
      for (int mi = 0; mi < 4; ++mi) {
        int row = mi * 16 + (lane & 15);
        af[mi] = *(const bf16x8*)((const char*)aL[kh][cur] + row * 128 + (cb ^ ((row & 7) << 4)));
      }
      {
        int row = ws2 * 16 + (lane & 15);
        bfr = *(const bf16x8*)((const char*)bL[kh][cur] + row * 128 + (cb ^ ((row & 7) << 4)));
      }
#pragma unroll
      for (int mi = 0; mi < 4; ++mi)
        acc[mi] = __builtin_amdgcn_mfma_f32_16x16x32_bf16(af[mi], bfr, acc[mi], 0, 0, 0);
    }
    __syncthreads();
    cur ^= 1;
  }

  float* mergeF = (float*)aL;
  const int r0l = (lane >> 4) << 2, col16 = lane & 15;
  if (kh == 1) {
#pragma unroll
    for (int mi = 0; mi < 4; ++mi)
#pragma unroll
      for (int r = 0; r < 4; ++r)
        mergeF[(ws2 * 64 + mi * 16 + r0l + r) * 17 + col16] = acc[mi][r];
  }
  __syncthreads();
  if (kh == 0) {
    int col = n0 + ws2 * 16 + col16;
    float bv = bias[col];
#pragma unroll
    for (int mi = 0; mi < 4; ++mi) {
      int row = m0 + mi * 16 + r0l;
#pragma unroll
      for (int r = 0; r < 4; ++r) {
        float v = acc[mi][r] + mergeF[(ws2 * 64 + mi * 16 + r0l + r) * 17 + col16] + bv;
        size_t idx = (size_t)(row + r) * N + col;
        if (MODE == 0) ((u16*)outv)[idx] = f2bf(v * scale);
        else ((float*)outv)[idx] = res[idx] + v;
      }
    }
  }
}

// ---------------- flash attention, split-KV x4, pipelined staging + lean softmax ----------
template <bool CAUSAL>
__global__ __launch_bounds__(512, 2) void k_attn3(const u16* __restrict__ Q, const u16* __restrict__ K,
                                                  const u16* __restrict__ VT, u16* __restrict__ O,
                                                  int S, int qstride, int kstride) {
  __shared__ __align__(16) char smem[64 * 1024 + 2048 + 8192];
  const int t = threadIdx.x, lane = t & 63, w = t >> 6;   // w 0..7
  const int ks = w & 3, qw = w >> 2;                      // split 0..3, q-wave 0..1
  const int lo5 = lane & 31, hi = lane >> 5;
  const int h = blockIdx.x;
  const int bq = blockIdx.y;
  const int qt = (bq & 1) ? (31 - (bq >> 1)) : (bq >> 1);
  const int hd0 = h * 64;
  const int q0 = qt * 64 + qw * 32;
  const int ts = qw * 64 + lane;                          // 0..127 within split

  u16* kL = (u16*)(smem + ks * 16384);
  u16* vL = (u16*)(smem + ks * 16384 + 8192);

  auto issueK = [&](int kt) {
#pragma unroll
    for (int j = 0; j < 4; ++j) {
      int c = j * 128 + ts, row = c >> 3, c16 = c & 7;
      int sw = (c16 * 16) ^ ((row & 7) << 4);
      gload16((const char*)(K + (size_t)(kt * 64 + row) * kstride + hd0) + sw, (char*)kL + c * 16);
    }
  };
  auto issueV = [&](int kt) {
#pragma unroll
    for (int j = 0; j < 4; ++j) {
      int c = j * 128 + ts, row = c >> 3, c16 = c & 7;
      int sw = (c16 * 16) ^ ((row & 7) << 4);
      gload16((const char*)(VT + (size_t)(hd0 + row) * S + kt * 64) + sw, (char*)vL + c * 16);
    }
  };

  bf16x8 qf[4];
#pragma unroll
  for (int sl = 0; sl < 4; ++sl)
    qf[sl] = *(const bf16x8*)(Q + (size_t)(q0 + lo5) * qstride + hd0 + sl * 16 + hi * 8);

  f32x16 oa0 = {}, oa1 = {};
  float mrun = -1e30f, lsum = 0.f;

  const int nkt = CAUSAL ? (qt + 1) : (S >> 6);
  const int nIter = (nkt + 3) >> 2;

  if (ks < nkt) { issueK(ks); issueV(ks); }
  __syncthreads();

  for (int i = 0; i < nIter; ++i) {
    const int kt = ks + 4 * i;
    const bool active = kt < nkt;
    const bool nxt = kt + 4 < nkt;
    f32x16 s0 = {}, s1 = {};
    if (active) {
      // QK^T: S^T[kv][q]
#pragma unroll
      for (int sl = 0; sl < 4; ++sl) {
        int cb = sl * 32 + hi * 16;
        int r0 = lo5, r1 = 32 + lo5;
        bf16x8 kf0 = *(const bf16x8*)((const char*)kL + r0 * 128 + (cb ^ ((r0 & 7) << 4)));
        bf16x8 kf1 = *(const bf16x8*)((const char*)kL + r1 * 128 + (cb ^ ((r1 & 7) << 4)));
        s0 = __builtin_amdgcn_mfma_f32_32x32x16_bf16(kf0, qf[sl], s0, 0, 0, 0);
        s1 = __builtin_amdgcn_mfma_f32_32x32x16_bf16(kf1, qf[sl], s1, 0, 0, 0);
      }
      if (CAUSAL && kt == qt) {
        int qg = q0 + lo5;
#pragma unroll
        for (int r = 0; r < 16; ++r) {
          int kg = kt * 64 + (r & 3) + 8 * (r >> 2) + 4 * hi;
          if (kg > qg) s0[r] = -1e30f;
          if (kg + 32 > qg) s1[r] = -1e30f;
        }
      }
      // tree max over 32 in-lane values + cross-half
      float mx[16];
#pragma unroll
      for (int r = 0; r < 16; ++r) mx[r] = fmaxf(s0[r], s1[r]);
#pragma unroll
      for (int st = 8; st; st >>= 1)
#pragma unroll
        for (int r = 0; r < 8; ++r)
          if (r < st) mx[r] = fmaxf(mx[r], mx[r + st]);
      float pm = fmaxf(mx[0], __shfl_xor(mx[0], 32));

      // defer-max (T13): skip rescale unless growth > 8 (exp2 domain)
      if (!__all(pm - mrun <= 8.f)) {
        float mnew = fmaxf(mrun, pm);
        float sc = exp2f(mrun - mnew);
        lsum *= sc;
#pragma unroll
        for (int r = 0; r < 16; ++r) { oa0[r] *= sc; oa1[r] *= sc; }
        mrun = mnew;
      }

#pragma unroll
      for (int r = 0; r < 16; ++r) s0[r] = exp2f(s0[r] - mrun);
#pragma unroll
      for (int r = 0; r < 16; ++r) s1[r] = exp2f(s1[r] - mrun);
      // tree sum
      float sm[16];
#pragma unroll
      for (int r = 0; r < 16; ++r) sm[r] = s0[r] + s1[r];
#pragma unroll
      for (int st = 8; st; st >>= 1)
#pragma unroll
        for (int r = 0; r < 8; ++r)
          if (r < st) sm[r] += sm[r + st];
      lsum += sm[0] + __shfl_xor(sm[0], 32);
    }
    __syncthreads();           // all kL reads done; drains V(kt)
    if (nxt) issueK(kt + 4);   // hidden under PV
    if (active) {
#pragma unroll
      for (int ksl = 0; ksl < 4; ++ksl) {
        const int base = 8 * (ksl & 1);
        float pA0, pA1, pA2, pA3, pB0, pB1, pB2, pB3;
        if (ksl < 2) {
          pA0 = s0[base + 0]; pA1 = s0[base + 1]; pA2 = s0[base + 2]; pA3 = s0[base + 3];
          pB0 = s0[base + 4]; pB1 = s0[base + 5]; pB2 = s0[base + 6]; pB3 = s0[base + 7];
        } else {
          pA0 = s1[base + 0]; pA1 = s1[base + 1]; pA2 = s1[base + 2]; pA3 = s1[base + 3];
          pB0 = s1[base + 4]; pB1 = s1[base + 5]; pB2 = s1[base + 6]; pB3 = s1[base + 7];
        }
        unsigned a01 = cvt_pk(pA0, pA1), a23 = cvt_pk(pA2, pA3);
        unsigned b01 = cvt_pk(pB0, pB1), b23 = cvt_pk(pB2, pB3);
        unsigned xa01 = __shfl_xor(a01, 32), xa23 = __shfl_xor(a23, 32);
        unsigned xb01 = __shfl_xor(b01, 32), xb23 = __shfl_xor(b23, 32);
        union { unsigned u[4]; bf16x8 v; } pf;
        pf.u[0] = hi ? xb01 : a01;
        pf.u[1] = hi ? xb23 : a23;
        pf.u[2] = hi ? b01 : xa01;
        pf.u[3] = hi ? b23 : xa23;
        int cb = ksl * 32 + hi * 16;
        int r0 = lo5, r1 = 32 + lo5;
        bf16x8 vf0 = *(const bf16x8*)((const char*)vL + r0 * 128 + (cb ^ ((r0 & 7) << 4)));
        bf16x8 vf1 = *(const bf16x8*)((const char*)vL + r1 * 128 + (cb ^ ((r1 & 7) << 4)));
        oa0 = __builtin_amdgcn_mfma_f32_32x32x16_bf16(vf0, pf.v, oa0, 0, 0, 0);
        oa1 = __builtin_amdgcn_mfma_f32_32x32x16_bf16(vf1, pf.v, oa1, 0, 0, 0);
      }
    }
    __syncthreads();           // all vL reads done; drains K(kt+4)
    if (nxt) issueV(kt + 4);   // hidden under next QK + softmax
  }
  __syncthreads();             // drain any last issues (none) + staging reads done

  // ---- merge across splits ----
  float* mlBuf = (float*)(smem + 65536);
#define OB_BYTE(g, halfoff) (lo5 * 256 + (((halfoff) + 32 * (g) + 16 * hi) ^ ((lo5 & 15) << 4)))
  if (ks >= 2) {
    char* ob = smem + (qw * 2 + (ks - 2)) * 8192;
#pragma unroll
    for (int g = 0; g < 4; ++g) {
      *(float4*)(ob + OB_BYTE(g, 0)) = make_float4(oa0[4 * g + 0], oa0[4 * g + 1], oa0[4 * g + 2], oa0[4 * g + 3]);
      *(float4*)(ob + OB_BYTE(g, 128)) = make_float4(oa1[4 * g + 0], oa1[4 * g + 1], oa1[4 * g + 2], oa1[4 * g + 3]);
    }
    if (hi == 0) { mlBuf[(w * 32 + lo5) * 2] = mrun; mlBuf[(w * 32 + lo5) * 2 + 1] = lsum; }
  }
  __syncthreads();
  if (ks < 2) {
    int pw = qw * 4 + ks + 2;
    char* ob = smem + (qw * 2 + ks) * 8192;
    float mB = mlBuf[(pw * 32 + lo5) * 2], lB = mlBuf[(pw * 32 + lo5) * 2 + 1];
    float M = fmaxf(mrun, mB);
    float sA = exp2f(mrun - M), sB = exp2f(mB - M);
    lsum = lsum * sA + lB * sB;
    mrun = M;
#pragma unroll
    for (int g = 0; g < 4; ++g) {
      float4 v0 = *(const float4*)(ob + OB_BYTE(g, 0));
      float4 v1 = *(const float4*)(ob + OB_BYTE(g, 128));
      oa0[4 * g + 0] = oa0[4 * g + 0] * sA + v0.x * sB;
      oa0[4 * g + 1] = oa0[4 * g + 1] * sA + v0.y * sB;
      oa0[4 * g + 2] = oa0[4 * g + 2] * sA + v0.z * sB;
      oa0[4 * g + 3] = oa0[4 * g + 3] * sA + v0.w * sB;
      oa1[4 * g + 0] = oa1[4 * g + 0] * sA + v1.x * sB;
      oa1[4 * g + 1] = oa1[4 * g + 1] * sA + v1.y * sB;
      oa1[4 * g + 2] = oa1[4 * g + 2] * sA + v1.z * sB;
      oa1[4 * g + 3] = oa1[4 * g + 3] * sA + v1.w * sB;
    }
  }
  if (ks == 1) {
    char* ob = smem + 32768 + qw * 8192;
#pragma unroll
    for (int g = 0; g < 4; ++g) {
      *(float4*)(ob + OB_BYTE(g, 0)) = make_float4(oa0[4 * g + 0], oa0[4 * g + 1], oa0[4 * g + 2], oa0[4 * g + 3]);
      *(float4*)(ob + OB_BYTE(g, 128)) = make_float4(oa1[4 * g + 0], oa1[4 * g + 1], oa1[4 * g + 2], oa1[4 * g + 3]);
    }
    if (hi == 0) { mlBuf[(w * 32 + lo5) * 2] = mrun; mlBuf[(w * 32 + lo5) * 2 + 1] = lsum; }
  }
  __syncthreads();
  if (ks == 0) {
    int pw = qw * 4 + 1;
    char* ob = smem + 32768 + qw * 8192;
    float mB = mlBuf[(pw * 32 + lo5) * 2], lB = mlBuf[(pw * 32 + lo5) * 2 + 1];
    float M = fmaxf(mrun, mB);
    float sA = exp2f(mrun - M), sB = exp2f(mB - M);
    lsum = lsum * sA + lB * sB;
#pragma unroll
    for (int g = 0; g < 4; ++g) {
      float4 v0 = *(const float4*)(ob + OB_BYTE(g, 0));
      float4 v1 = *(const float4*)(ob + OB_BYTE(g, 128));
      oa0[4 * g + 0] = oa0[4 * g + 0] * sA + v0.x * sB;
      oa0[4 * g + 1] = oa0[4 * g + 1] * sA + v0.y * sB;
      oa0[4 * g + 2] = oa0[4 * g + 2] * sA + v0.z * sB;
      oa0[4 * g + 3] = oa0[4 * g + 3] * sA + v0.w * sB;
      oa1[4 * g + 0] = oa1[4 * g + 0] * sA + v1.x * sB;
      oa1[4 * g + 1] = oa1[4 * g + 1] * sA + v1.y * sB;
      oa1[4 * g + 2] = oa1[4 * g + 2] * sA + v1.z * sB;
      oa1[4 * g + 3] = oa1[4 * g + 3] * sA + v1.w * sB;
    }
    float inv = 1.f / lsum;
    u16* ldsO = (u16*)(smem + 65536 + 2048);
    int qrow = qw * 32 + lo5;
#pragma unroll
    for (int g = 0; g < 4; ++g) {
      unsigned w0 = cvt_pk(oa0[4 * g + 0] * inv, oa0[4 * g + 1] * inv);
      unsigned w1 = cvt_pk(oa0[4 * g + 2] * inv, oa0[4 * g + 3] * inv);
      int dby = (8 * g + 4 * hi) * 2;
      *(uint2*)((char*)ldsO + qrow * 128 + (dby ^ ((qrow & 7) << 4))) = make_uint2(w0, w1);
      unsigned w2 = cvt_pk(oa1[4 * g + 0] * inv, oa1[4 * g + 1] * inv);
      unsigned w3 = cvt_pk(oa1[4 * g + 2] * inv, oa1[4 * g + 3] * inv);
      int dby2 = (32 + 8 * g + 4 * hi) * 2;
      *(uint2*)((char*)ldsO + qrow * 128 + (dby2 ^ ((qrow & 7) << 4))) = make_uint2(w2, w3);
    }
  }
  __syncthreads();
  {
    u16* ldsO = (u16*)(smem + 65536 + 2048);
    int c = t, row = c >> 3, c16 = c & 7;
    uint4 val = *(const uint4*)((const char*)ldsO + row * 128 + ((c16 * 16) ^ ((row & 7) << 4)));
    *(uint4*)(O + (size_t)(qt * 64 + row) * 1024 + hd0 + c16 * 8) = val;
  }
#undef OB_BYTE
}

// ==========================================================================================
extern "C" void kernel_launch(void* const* d_in, const int* in_sizes, int n_in,
                              void* d_out, int out_size, void* d_ws, size_t ws_size,
                              hipStream_t stream) {
  const float* features = (const float*)d_in[0];
  const float* enc      = (const float*)d_in[1];
  const float* g1a = (const float*)d_in[2];  const float* b1a = (const float*)d_in[3];
  const float* g1b = (const float*)d_in[4];  const float* b1b = (const float*)d_in[5];
  const float* g2a = (const float*)d_in[6];  const float* b2a = (const float*)d_in[7];
  const float* g2b = (const float*)d_in[8];  const float* b2b = (const float*)d_in[9];
  const float* sa_qw = (const float*)d_in[10]; const float* sa_qb = (const float*)d_in[11];
  const float* sa_kw = (const float*)d_in[12]; const float* sa_kb = (const float*)d_in[13];
  const float* sa_vw = (const float*)d_in[14]; const float* sa_vb = (const float*)d_in[15];
  const float* sa_pw = (const float*)d_in[16]; const float* sa_pb = (const float*)d_in[17];
  const float* ca_qw = (const float*)d_in[18]; const float* ca_qb = (const float*)d_in[19];
  const float* ca_kw = (const float*)d_in[20]; const float* ca_kb = (const float*)d_in[21];
  const float* ca_vw = (const float*)d_in[22]; const float* ca_vb = (const float*)d_in[23];
  const float* ca_pw = (const float*)d_in[24]; const float* ca_pb = (const float*)d_in[25];
  const float* m1_w1 = (const float*)d_in[26]; const float* m1_b1 = (const float*)d_in[27];
  const float* m1_w2 = (const float*)d_in[28]; const float* m1_b2 = (const float*)d_in[29];
  const float* m2_w1 = (const float*)d_in[30]; const float* m2_b1 = (const float*)d_in[31];
  const float* m2_w2 = (const float*)d_in[32]; const float* m2_b2 = (const float*)d_in[33];

  const int S = 2048, C = 1024, Mh = 4096;
  const size_t CC = (size_t)C * C;
  float* xout = (float*)d_out;

  char* p = (char*)d_ws;
  auto take = [&](size_t bytes) { char* q = p; p += (bytes + 255) & ~(size_t)255; return q; };
  u16* wt_qkv  = (u16*)take(3 * CC * 2);
  u16* wt_sap  = (u16*)take(CC * 2);
  u16* wt_cap  = (u16*)take(CC * 2);
  u16* wt_caq  = (u16*)take(CC * 2);
  u16* wt_ckv  = (u16*)take(2 * CC * 2);
  u16* wt_m1w1 = (u16*)take((size_t)C * Mh * 2);
  u16* wt_m1w2 = (u16*)take((size_t)C * Mh * 2);
  u16* wt_m2w1 = (u16*)take((size_t)C * Mh * 2);
  u16* wt_m2w2 = (u16*)take((size_t)C * Mh * 2);
  float* bias_qkv = (float*)take(3 * C * 4);
  float* bias_ckv = (float*)take(2 * C * 4);
  u16* xn   = (u16*)take((size_t)S * C * 2);
  u16* encb = (u16*)take((size_t)S * C * 2);
  u16* vtbuf = (u16*)take((size_t)C * S * 2);
  u16* abuf  = (u16*)take((size_t)S * C * 2);
  u16* hbuf  = (u16*)take((size_t)S * Mh * 2);
  u16* qkbuf = hbuf;
  u16* qbuf  = hbuf + (size_t)4 * 1024 * 1024;
  u16* kvbuf = hbuf + (size_t)6 * 1024 * 1024;

  dim3 blk(256);
  const float qs2 = 0.125f * 1.4426950408889634f;
  const int BIG = 1 << 30;

  TransArgs ta;
  ta.src[0] = sa_qw;  ta.dst[0] = wt_qkv;
  ta.src[1] = sa_kw;  ta.dst[1] = wt_qkv + CC;
  ta.src[2] = sa_vw;  ta.dst[2] = wt_qkv + 2 * CC;
  ta.src[3] = sa_pw;  ta.dst[3] = wt_sap;
  ta.src[4] = ca_pw;  ta.dst[4] = wt_cap;
  ta.src[5] = ca_qw;  ta.dst[5] = wt_caq;
  ta.src[6] = ca_kw;  ta.dst[6] = wt_ckv;
  ta.src[7] = ca_vw;  ta.dst[7] = wt_ckv + CC;
  ta.src[8] = m1_w1;  ta.dst[8] = wt_m1w1;
  ta.src[9] = m1_w2;  ta.dst[9] = wt_m1w2;
  ta.src[10] = m2_w1; ta.dst[10] = wt_m2w1;
  ta.src[11] = m2_w2; ta.dst[11] = wt_m2w2;
  k_transpose_all<<<dim3(8192 + 16384), blk, 0, stream>>>(ta);
  k_cvt<<<dim3(S * C / 1024), blk, 0, stream>>>(enc, encb, S * C / 4);
  k_biaspack<<<20, blk, 0, stream>>>(bias_qkv, bias_ckv, sa_qb, sa_kb, sa_vb, ca_kb, ca_vb);

  // --- block 1: self-attention (causal)
  k_ln<<<S, blk, 0, stream>>>(features, g1a, b1a, xn);
  k_gemm<0><<<dim3(24, 32), blk, 0, stream>>>(xn, wt_qkv, bias_qkv, qkbuf, vtbuf,
                                              S, 3072, C, 2048, qs2, 1024, 2048);
  k_attn3<true><<<dim3(16, 32), dim3(512), 0, stream>>>(qkbuf, qkbuf + 1024, vtbuf, abuf, S, 2048, 2048);
  k_gemm_sk<1><<<dim3(16, 32), dim3(512), 0, stream>>>(abuf, wt_sap, sa_pb, features, xout, S, C, C, 1.f);
  // --- MLP 1
  k_ln<<<S, blk, 0, stream>>>(xout, g1b, b1b, xn);
  k_gemm<2><<<dim3(32, 32), blk, 0, stream>>>(xn, wt_m1w1, m1_b1, hbuf, nullptr,
                                              S, Mh, C, Mh, 1.f, 0, BIG);
  k_gemm_sk<1><<<dim3(16, 32), dim3(512), 0, stream>>>(hbuf, wt_m1w2, m1_b2, xout, xout, S, C, Mh, 1.f);
  // --- block 2: cross-attention
  k_ln<<<S, blk, 0, stream>>>(xout, g2a, b2a, xn);
  k_gemm_sk<0><<<dim3(16, 32), dim3(512), 0, stream>>>(xn, wt_caq, ca_qb, nullptr, qbuf, S, C, C, qs2);
  k_gemm<0><<<dim3(16, 32), blk, 0, stream>>>(encb, wt_ckv, bias_ckv, kvbuf, vtbuf,
                                              S, 2048, C, 1024, 1.f, 0, 1024);
  k_attn3<false><<<dim3(16, 32), dim3(512), 0, stream>>>(qbuf, kvbuf, vtbuf, abuf, S, 1024, 1024);
  k_gemm_sk<1><<<dim3(16, 32), dim3(512), 0, stream>>>(abuf, wt_cap, ca_pb, xout, xout, S, C, C, 1.f);
  // --- MLP 2
  k_ln<<<S, blk, 0, stream>>>(xout, g2b, b2b, xn);
  k_gemm<2><<<dim3(32, 32), blk, 0, stream>>>(xn, wt_m2w1, m2_b1, hbuf, nullptr,
                                              S, Mh, C, Mh, 1.f, 0, BIG);
  k_gemm_sk<1><<<dim3(16, 32), dim3(512), 0, stream>>>(hbuf, wt_m2w2, m2_b2, xout, xout, S, C, Mh, 1.f);
}